// Round 11
// baseline (1485.053 us; speedup 1.0000x reference)
//
#include <hip/hip_runtime.h>

typedef unsigned int u32;
typedef unsigned short u16;

#define ND 50000
#define NF 50000
#define NE 800000
#define DD 64
#define NBLK 196   // ceil(50000/256)
#define EBLK 3125  // 800000/256

// ---- ws float-index layout (8,200,064 floats = 32.8 MB < proven 38.9 MB) ----
#define OFF_FLAGS 0                        // [0] = idx-is-int64
#define OFF_CNTN  64                       // 50000 int
#define OFF_CNTF  (OFF_CNTN + 50000)       // 50000 int
#define OFF_STAN  (OFF_CNTF + 50000)       // 50000 int (after fill: end offsets)
#define OFF_STAF  (OFF_STAN + 50000)       // 50000 int
#define OFF_OTHN  (OFF_STAF + 50000)       // 800000 int: dst of edge at CSR slot i (N side)
#define OFF_OTHF  (OFF_OTHN + 800000)      // 800000 int: src of edge at CSR slot i (F side)
#define OFF_MSGN  (OFF_OTHF + 800000)      // 3.2M f: msg sums; first 1.6M floats hold posN/posF
                                           //   during fill->ep (dead before gatherN writes msgN)
#define OFF_MSGF  (OFF_MSGN + 3200000)     // 3.2M f: msg sums; rows later hold FOw bf16
#define WS_FLOATS (OFF_MSGF + 3200000)

// d_out overlays (strictly ordered across kernel boundaries):
//   node region   [0, 3.2M floats)     : Fp bf16 -> overwritten by upd-node
//   edge region   [3.2M, 28.8M floats) : epN bf16 (CSR-sorted, N side) -> overwritten by k_eout
//                 [28.8M, 54.4M)       : epF bf16 (CSR-sorted, F side) -> overwritten by k_eout
//   feature region[54.4M, 57.6M)       : Np bf16 -> overwritten by upd-feat

__device__ __forceinline__ u16 f2bf(float x){ union{u32 u;float f;}v; v.f=x; u32 r=v.u+0x7fffu+((v.u>>16)&1u); return (u16)(r>>16); }
__device__ __forceinline__ float bf2f(u16 h){ union{u32 u;float f;}v; v.u=((u32)h)<<16; return v.f; }
__device__ __forceinline__ u32 pk2(float a,float b){ return (u32)f2bf(a) | ((u32)f2bf(b)<<16); }

// full-width (64-col) gemv from global — used by k_upd (round-7 proven)
__device__ __forceinline__ void gemv_f32(const float* __restrict__ x,
                                         const float* __restrict__ wt,
                                         float acc[DD]) {
  #pragma unroll 4
  for (int k4 = 0; k4 < 16; ++k4) {
    const float4 v = *(const float4*)(x + k4*4);
    const float f[4] = {v.x, v.y, v.z, v.w};
    const float* __restrict__ wr = wt + k4*4*DD;
    #pragma unroll
    for (int c = 0; c < DD; ++c) {
      float a = acc[c];
      #pragma unroll
      for (int j = 0; j < 4; ++j) a = fmaf(f[j], wr[j*DD + c], a);
      acc[c] = a;
    }
  }
}

// register-input gemv; k ascending — same summation order as gemv_f32
__device__ __forceinline__ void gemv_reg(const float x[DD],
                                         const float* __restrict__ wt,
                                         float acc[DD]) {
  #pragma unroll 8
  for (int k = 0; k < DD; ++k) {
    const float fk = x[k];
    const float* __restrict__ wr = wt + k*DD;
    #pragma unroll
    for (int c = 0; c < DD; ++c) acc[c] = fmaf(fk, wr[c], acc[c]);
  }
}

__device__ __forceinline__ void store_row(float* __restrict__ o, const float acc[DD]) {
  float4* o4 = (float4*)o;
  #pragma unroll
  for (int i = 0; i < 16; ++i)
    o4[i] = make_float4(acc[4*i], acc[4*i+1], acc[4*i+2], acc[4*i+3]);
}

// 64 fp32 -> 64 bf16 (128B) contiguous row store (k_upd)
__device__ __forceinline__ void store_h_row(u16* __restrict__ o, const float acc[DD]) {
  uint4 s[8]; u32* sw = (u32*)s;
  #pragma unroll
  for (int i = 0; i < 32; ++i) sw[i] = pk2(acc[2*i], acc[2*i+1]);
  uint4* o4 = (uint4*)o;
  #pragma unroll
  for (int i = 0; i < 8; ++i) o4[i] = s[i];
}

// int64 edge_index => every odd u32 word is 0
__global__ __launch_bounds__(256) void k_detect(const u32* __restrict__ idxw,
                                                int* __restrict__ flags) {
  __shared__ int cn;
  if (threadIdx.x == 0) cn = 0;
  __syncthreads();
  int c = 0;
  for (int k = 0; k < 16; ++k)
    c += (idxw[2*(threadIdx.x + k*256) + 1] != 0u) ? 1 : 0;
  atomicAdd(&cn, c);
  __syncthreads();
  if (threadIdx.x == 0) flags[0] = (cn == 0) ? 1 : 0;
}

__global__ __launch_bounds__(256) void k_hist(const u32* __restrict__ eidx,
                                              int* __restrict__ cntN,
                                              int* __restrict__ cntF,
                                              const int* __restrict__ flags) {
  const int e = blockIdx.x*256 + threadIdx.x;
  const int I64 = flags[0];
  const u32 src = I64 ? eidx[2*(size_t)e]        : eidx[e];
  const u32 dst = I64 ? eidx[2*((size_t)NE + e)] : eidx[(size_t)NE + e];
  atomicAdd(cntN + src, 1);
  atomicAdd(cntF + dst, 1);
}

// exclusive prefix sum of 50000 ints; block 0 -> (cntN->staN), block 1 -> (cntF->staF)
__global__ __launch_bounds__(1024) void k_scan(const int* __restrict__ cnt,
                                               int* __restrict__ sta) {
  const int base = blockIdx.x * 50000;
  const int t = threadIdx.x;
  __shared__ int part[1024];
  int local[49];
  int s = 0;
  const int start = t * 49;
  #pragma unroll
  for (int j = 0; j < 49; ++j) {
    const int idx = start + j;
    const int v = (idx < 50000) ? cnt[base + idx] : 0;
    local[j] = s;
    s += v;
  }
  part[t] = s;
  __syncthreads();
  for (int off = 1; off < 1024; off <<= 1) {
    int v = 0;
    if (t >= off) v = part[t - off];
    __syncthreads();
    if (t >= off) part[t] += v;
    __syncthreads();
  }
  const int bv = (t > 0) ? part[t - 1] : 0;
  #pragma unroll
  for (int j = 0; j < 49; ++j) {
    const int idx = start + j;
    if (idx < 50000) sta[base + idx] = bv + local[j];
  }
}

// CSR fill; also records each edge's slot (pos) and the gather-side node (oth)
__global__ __launch_bounds__(256) void k_fill(const u32* __restrict__ eidx,
                                              int* __restrict__ staN,
                                              int* __restrict__ staF,
                                              int* __restrict__ othN,
                                              int* __restrict__ othF,
                                              int* __restrict__ posN,
                                              int* __restrict__ posF,
                                              const int* __restrict__ flags) {
  const int e = blockIdx.x*256 + threadIdx.x;
  const int I64 = flags[0];
  const u32 src = I64 ? eidx[2*(size_t)e]        : eidx[e];
  const u32 dst = I64 ? eidx[2*((size_t)NE + e)] : eidx[(size_t)NE + e];
  const int pN = atomicAdd(staN + src, 1);
  const int pF = atomicAdd(staF + dst, 1);
  othN[pN] = (int)dst;
  othF[pF] = (int)src;
  posN[e] = pN;
  posF[e] = pF;
}

// ---- transposed-GEMV kernels: 4 rows per wave, lane = (r=lane>>4, m=lane&15).
// Each lane computes cols [4m,4m+4) of row r via ds_bpermute row-broadcast.
// k ascending -> bit-identical summation to gemv_f32.

// proj[row] (bf16) = emb[row] @ wt ; 16 rows per 256-thread block (50000 = 3125*16)
__global__ __launch_bounds__(256) void k_proj4(const float* __restrict__ emb,
                                               const float* __restrict__ wt,
                                               u16* __restrict__ outp) {
  const int wid = (blockIdx.x*256 + threadIdx.x) >> 6;
  const int lane = threadIdx.x & 63;
  const int m = lane & 15, r = lane >> 4;
  const int nb = wid << 2;
  const int n = nb + r;
  const float4 vx = *(const float4*)(emb + (size_t)nb*DD + lane*4);
  float a0 = 0.f, a1 = 0.f, a2 = 0.f, a3 = 0.f;
  const int abase = (lane & 48) << 2;
  #pragma unroll
  for (int k4 = 0; k4 < 16; ++k4) {
    const int addr = abase | (k4 << 2);
    const float x0 = __int_as_float(__builtin_amdgcn_ds_bpermute(addr, __float_as_int(vx.x)));
    const float x1 = __int_as_float(__builtin_amdgcn_ds_bpermute(addr, __float_as_int(vx.y)));
    const float x2 = __int_as_float(__builtin_amdgcn_ds_bpermute(addr, __float_as_int(vx.z)));
    const float x3 = __int_as_float(__builtin_amdgcn_ds_bpermute(addr, __float_as_int(vx.w)));
    const float4 w0 = *(const float4*)(wt + (size_t)(4*k4+0)*DD + 4*m);
    const float4 w1 = *(const float4*)(wt + (size_t)(4*k4+1)*DD + 4*m);
    const float4 w2 = *(const float4*)(wt + (size_t)(4*k4+2)*DD + 4*m);
    const float4 w3 = *(const float4*)(wt + (size_t)(4*k4+3)*DD + 4*m);
    a0 = fmaf(x0, w0.x, a0); a1 = fmaf(x0, w0.y, a1); a2 = fmaf(x0, w0.z, a2); a3 = fmaf(x0, w0.w, a3);
    a0 = fmaf(x1, w1.x, a0); a1 = fmaf(x1, w1.y, a1); a2 = fmaf(x1, w1.z, a2); a3 = fmaf(x1, w1.w, a3);
    a0 = fmaf(x2, w2.x, a0); a1 = fmaf(x2, w2.y, a1); a2 = fmaf(x2, w2.z, a2); a3 = fmaf(x2, w2.w, a3);
    a0 = fmaf(x3, w3.x, a0); a1 = fmaf(x3, w3.y, a1); a2 = fmaf(x3, w3.z, a2); a3 = fmaf(x3, w3.w, a3);
  }
  *(uint2*)(outp + (size_t)n*DD + m*4) = make_uint2(pk2(a0, a1), pk2(a2, a3));
}

// ep row = eemb[e] @ P1 + bP, written twice CSR-sorted; 16 edges/block (800000 = 50000*16)
__global__ __launch_bounds__(256) void k_ep4(const float* __restrict__ eemb,
                                             const float* __restrict__ P1,
                                             const float* __restrict__ bP,
                                             const int* __restrict__ posN,
                                             const int* __restrict__ posF,
                                             u16* __restrict__ epN,
                                             u16* __restrict__ epF) {
  const int wid = (blockIdx.x*256 + threadIdx.x) >> 6;
  const int lane = threadIdx.x & 63;
  const int m = lane & 15, r = lane >> 4;
  const int eb = wid << 2;
  const int e = eb + r;
  const float4 vx = *(const float4*)(eemb + (size_t)eb*DD + lane*4);
  float a0, a1, a2, a3;
  { const float4 b = *(const float4*)(bP + 4*m); a0 = b.x; a1 = b.y; a2 = b.z; a3 = b.w; }
  const int abase = (lane & 48) << 2;
  #pragma unroll
  for (int k4 = 0; k4 < 16; ++k4) {
    const int addr = abase | (k4 << 2);
    const float x0 = __int_as_float(__builtin_amdgcn_ds_bpermute(addr, __float_as_int(vx.x)));
    const float x1 = __int_as_float(__builtin_amdgcn_ds_bpermute(addr, __float_as_int(vx.y)));
    const float x2 = __int_as_float(__builtin_amdgcn_ds_bpermute(addr, __float_as_int(vx.z)));
    const float x3 = __int_as_float(__builtin_amdgcn_ds_bpermute(addr, __float_as_int(vx.w)));
    const float4 w0 = *(const float4*)(P1 + (size_t)(4*k4+0)*DD + 4*m);
    const float4 w1 = *(const float4*)(P1 + (size_t)(4*k4+1)*DD + 4*m);
    const float4 w2 = *(const float4*)(P1 + (size_t)(4*k4+2)*DD + 4*m);
    const float4 w3 = *(const float4*)(P1 + (size_t)(4*k4+3)*DD + 4*m);
    a0 = fmaf(x0, w0.x, a0); a1 = fmaf(x0, w0.y, a1); a2 = fmaf(x0, w0.z, a2); a3 = fmaf(x0, w0.w, a3);
    a0 = fmaf(x1, w1.x, a0); a1 = fmaf(x1, w1.y, a1); a2 = fmaf(x1, w1.z, a2); a3 = fmaf(x1, w1.w, a3);
    a0 = fmaf(x2, w2.x, a0); a1 = fmaf(x2, w2.y, a1); a2 = fmaf(x2, w2.z, a2); a3 = fmaf(x2, w2.w, a3);
    a0 = fmaf(x3, w3.x, a0); a1 = fmaf(x3, w3.y, a1); a2 = fmaf(x3, w3.z, a2); a3 = fmaf(x3, w3.w, a3);
  }
  const uint2 pkd = make_uint2(pk2(a0, a1), pk2(a2, a3));
  const int pN = posN[e];
  *(uint2*)(epN + (size_t)pN*DD + m*4) = pkd;
  const int pF = posF[e];
  *(uint2*)(epF + (size_t)pF*DD + m*4) = pkd;
}

// fused edge_out = eemb@W0 + bW + NOw[src] + FOw[dst]; 16 edges/block
__global__ __launch_bounds__(256) void k_eout4(const float* __restrict__ eemb,
                                               const u32* __restrict__ eidx,
                                               const float* __restrict__ W,
                                               const float* __restrict__ bW,
                                               const u16* __restrict__ NOw,  // stride 128 u16/row
                                               const u16* __restrict__ FOw,
                                               float* __restrict__ outp,
                                               const int* __restrict__ flags) {
  const int wid = (blockIdx.x*256 + threadIdx.x) >> 6;
  const int lane = threadIdx.x & 63;
  const int m = lane & 15, r = lane >> 4;
  const int eb = wid << 2;
  const int e = eb + r;
  const int I64 = flags[0];
  const u32 src = I64 ? eidx[2*(size_t)e]        : eidx[e];
  const u32 dst = I64 ? eidx[2*((size_t)NE + e)] : eidx[(size_t)NE + e];
  const float4 vx = *(const float4*)(eemb + (size_t)eb*DD + lane*4);
  float a0, a1, a2, a3;
  { const float4 b = *(const float4*)(bW + 4*m); a0 = b.x; a1 = b.y; a2 = b.z; a3 = b.w; }
  const int abase = (lane & 48) << 2;
  #pragma unroll
  for (int k4 = 0; k4 < 16; ++k4) {
    const int addr = abase | (k4 << 2);
    const float x0 = __int_as_float(__builtin_amdgcn_ds_bpermute(addr, __float_as_int(vx.x)));
    const float x1 = __int_as_float(__builtin_amdgcn_ds_bpermute(addr, __float_as_int(vx.y)));
    const float x2 = __int_as_float(__builtin_amdgcn_ds_bpermute(addr, __float_as_int(vx.z)));
    const float x3 = __int_as_float(__builtin_amdgcn_ds_bpermute(addr, __float_as_int(vx.w)));
    const float4 w0 = *(const float4*)(W + (size_t)(4*k4+0)*DD + 4*m);
    const float4 w1 = *(const float4*)(W + (size_t)(4*k4+1)*DD + 4*m);
    const float4 w2 = *(const float4*)(W + (size_t)(4*k4+2)*DD + 4*m);
    const float4 w3 = *(const float4*)(W + (size_t)(4*k4+3)*DD + 4*m);
    a0 = fmaf(x0, w0.x, a0); a1 = fmaf(x0, w0.y, a1); a2 = fmaf(x0, w0.z, a2); a3 = fmaf(x0, w0.w, a3);
    a0 = fmaf(x1, w1.x, a0); a1 = fmaf(x1, w1.y, a1); a2 = fmaf(x1, w1.z, a2); a3 = fmaf(x1, w1.w, a3);
    a0 = fmaf(x2, w2.x, a0); a1 = fmaf(x2, w2.y, a1); a2 = fmaf(x2, w2.z, a2); a3 = fmaf(x2, w2.w, a3);
    a0 = fmaf(x3, w3.x, a0); a1 = fmaf(x3, w3.y, a1); a2 = fmaf(x3, w3.z, a2); a3 = fmaf(x3, w3.w, a3);
  }
  // gather adds: one uint2 (4 bf16 cols) per lane; 16 lanes cover the 128B row
  const uint2 ga = *(const uint2*)(NOw + (size_t)src*128 + m*4);
  a0 += bf2f((u16)(ga.x & 0xffffu)); a1 += bf2f((u16)(ga.x >> 16));
  a2 += bf2f((u16)(ga.y & 0xffffu)); a3 += bf2f((u16)(ga.y >> 16));
  const uint2 gb = *(const uint2*)(FOw + (size_t)dst*128 + m*4);
  a0 += bf2f((u16)(gb.x & 0xffffu)); a1 += bf2f((u16)(gb.x >> 16));
  a2 += bf2f((u16)(gb.y & 0xffffu)); a3 += bf2f((u16)(gb.y >> 16));
  *(float4*)(outp + (size_t)e*DD + 4*m) = make_float4(a0, a1, a2, a3);
}

// one wave per node: msg[n] = SUM over CSR range of relu(eps[i] + proj[oth[i]])
__global__ __launch_bounds__(256) void k_gather2(const int* __restrict__ sta,
                                                 const int* __restrict__ cnt,
                                                 const int* __restrict__ oth,
                                                 const u16* __restrict__ eps,
                                                 const u16* __restrict__ proj,
                                                 float* __restrict__ msg) {
  const int n = blockIdx.x*4 + (threadIdx.x >> 6);
  const int lane = threadIdx.x & 63;
  const int end = sta[n];
  const int c = cnt[n];
  float acc = 0.f;
  #pragma unroll 4
  for (int i = end - c; i < end; ++i) {
    const int o = oth[i];
    acc += fmaxf(bf2f(eps[(size_t)i*DD + lane]) + bf2f(proj[(size_t)o*DD + lane]), 0.f);
  }
  msg[(size_t)n*DD + lane] = acc;   // SUM; single division happens in k_upd
}

// out = emb@Q0 + mean_msg@Q1 + bQ ; then (out@Wseg) as bf16 in-place over msg row
__global__ __launch_bounds__(256) void k_upd(const float* __restrict__ emb,
                                             float* msgp,            // aliased in/out
                                             const int* __restrict__ cnt,
                                             const float* __restrict__ Q,
                                             const float* __restrict__ bQ,
                                             const float* __restrict__ Wseg,
                                             float* __restrict__ outp) {
  const int row = blockIdx.x*256 + threadIdx.x;
  if (row >= 50000) return;
  const float inv = 1.f / fmaxf((float)cnt[row], 1.f);
  float m[DD];
  {
    const float4* mp = (const float4*)(msgp + (size_t)row*DD);
    #pragma unroll
    for (int i = 0; i < 16; ++i) {
      const float4 v = mp[i];
      m[4*i] = v.x*inv; m[4*i+1] = v.y*inv; m[4*i+2] = v.z*inv; m[4*i+3] = v.w*inv;
    }
  }
  float acc[DD];
  #pragma unroll
  for (int c = 0; c < DD; ++c) acc[c] = bQ[c];
  gemv_f32(emb + (size_t)row*DD, Q, acc);
  gemv_reg(m, Q + 64*DD, acc);
  store_row(outp + (size_t)row*DD, acc);

  float acc2[DD];
  #pragma unroll
  for (int c = 0; c < DD; ++c) acc2[c] = 0.f;
  gemv_reg(acc, Wseg, acc2);
  // bf16 projection row stored over the START of this thread's own msg row
  store_h_row((u16*)(msgp + (size_t)row*DD), acc2);
}

extern "C" void kernel_launch(void* const* d_in, const int* in_sizes, int n_in,
                              void* d_out, int out_size, void* d_ws, size_t ws_size,
                              hipStream_t stream) {
  if (ws_size < (size_t)WS_FLOATS * 4) return;
  const float* node = (const float*)d_in[0];
  const float* eemb = (const float*)d_in[1];
  const float* feat = (const float*)d_in[2];
  const u32*   eidx = (const u32*)d_in[3];
  const float* P  = (const float*)d_in[4];
  const float* bP = (const float*)d_in[5];
  const float* Q  = (const float*)d_in[6];
  const float* bQ = (const float*)d_in[7];
  const float* W  = (const float*)d_in[8];
  const float* bW = (const float*)d_in[9];
  float* wsf = (float*)d_ws;
  int*   wsi = (int*)d_ws;
  float* out = (float*)d_out;

  u16* Fp_h = (u16*)out;                           // node region (bf16, half used)
  u16* epN_h = (u16*)(out + (size_t)ND*DD);        // edge region: CSR-sorted ep (N side)
  u16* epF_h = epN_h + (size_t)NE*DD;              // edge region: CSR-sorted ep (F side)
  u16* Np_h = (u16*)(out + (size_t)(ND + NE)*DD);  // feature region (bf16, half used)
  float* msgN = wsf + OFF_MSGN;
  float* msgF = wsf + OFF_MSGF;
  int* posN = (int*)(wsf + OFF_MSGN);              // overlays msgN start; dead after k_ep4
  int* posF = posN + NE;

  hipMemsetAsync((void*)(wsi + OFF_CNTN), 0, (size_t)100000 * 4, stream);
  k_detect<<<1, 256, 0, stream>>>(eidx, wsi + OFF_FLAGS);
  k_hist<<<EBLK, 256, 0, stream>>>(eidx, wsi + OFF_CNTN, wsi + OFF_CNTF, wsi + OFF_FLAGS);
  k_scan<<<2, 1024, 0, stream>>>(wsi + OFF_CNTN, wsi + OFF_STAN);
  k_fill<<<EBLK, 256, 0, stream>>>(eidx, wsi + OFF_STAN, wsi + OFF_STAF,
                                   wsi + OFF_OTHN, wsi + OFF_OTHF,
                                   posN, posF, wsi + OFF_FLAGS);
  k_proj4<<<3125, 256, 0, stream>>>(feat, P, Fp_h);
  k_proj4<<<3125, 256, 0, stream>>>(node, P, Np_h);
  k_ep4<<<50000, 256, 0, stream>>>(eemb, P + 64*DD, bP, posN, posF, epN_h, epF_h);
  // gatherN overwrites the pos arrays (dead after k_ep4)
  k_gather2<<<12500, 256, 0, stream>>>(wsi + OFF_STAN, wsi + OFF_CNTN,
                                       wsi + OFF_OTHN, epN_h, Fp_h, msgN);
  k_gather2<<<12500, 256, 0, stream>>>(wsi + OFF_STAF, wsi + OFF_CNTF,
                                       wsi + OFF_OTHF, epF_h, Np_h, msgF);
  // upd-feat first (overwrites Np region); then upd-node (overwrites Fp region)
  k_upd<<<NBLK, 256, 0, stream>>>(feat, msgF, wsi + OFF_CNTF, Q, bQ, W + 128*DD,
                                  out + (size_t)(ND + NE)*DD);
  k_upd<<<NBLK, 256, 0, stream>>>(node, msgN, wsi + OFF_CNTN, Q, bQ, W + 64*DD, out);
  // fused edge_out overwrites ep region
  k_eout4<<<50000, 256, 0, stream>>>(eemb, eidx, W, bW,
                                     (const u16*)msgN, (const u16*)msgF,
                                     out + (size_t)ND*DD, wsi + OFF_FLAGS);
}

// Round 12
// 929.814 us; speedup vs baseline: 1.5972x; 1.5972x over previous
//
#include <hip/hip_runtime.h>

typedef unsigned int u32;
typedef unsigned short u16;
using bf16x8 = __attribute__((ext_vector_type(8))) short;
using f32x4  = __attribute__((ext_vector_type(4))) float;

#define ND 50000
#define NF 50000
#define NE 800000
#define DD 64
#define NBLK 196   // ceil(50000/256)
#define EBLK 3125  // 800000/256

// ---- ws float-index layout ----
#define OFF_FLAGS 0                        // [0] = idx-is-int64
#define OFF_CNTN  64
#define OFF_CNTF  (OFF_CNTN + 50000)
#define OFF_STAN  (OFF_CNTF + 50000)
#define OFF_STAF  (OFF_STAN + 50000)
#define OFF_OTHN  (OFF_STAF + 50000)
#define OFF_OTHF  (OFF_OTHN + 800000)
#define OFF_MSGN  (OFF_OTHF + 800000)
#define OFF_MSGF  (OFF_MSGN + 3200000)
#define OFF_BPK   (OFF_MSGF + 3200000)     // 2048 floats: 4096 bf16 B-fragments of P1
#define WS_FLOATS (OFF_BPK + 2048)

// d_out overlays (strictly ordered across kernel boundaries) — as round 10.

__device__ __forceinline__ u16 f2bf(float x){ union{u32 u;float f;}v; v.f=x; u32 r=v.u+0x7fffu+((v.u>>16)&1u); return (u16)(r>>16); }
__device__ __forceinline__ float bf2f(u16 h){ union{u32 u;float f;}v; v.u=((u32)h)<<16; return v.f; }
__device__ __forceinline__ u32 pk2(float a,float b){ return (u32)f2bf(a) | ((u32)f2bf(b)<<16); }

// swizzled LDS byte offset for 64x128B tile (guide G4 attn pattern)
#define LDSW(row, b) ((row)*128 + ((b) ^ (((row)&7)<<4)))

__device__ __forceinline__ void gemv_f32(const float* __restrict__ x,
                                         const float* __restrict__ wt,
                                         float acc[DD]) {
  #pragma unroll 4
  for (int k4 = 0; k4 < 16; ++k4) {
    const float4 v = *(const float4*)(x + k4*4);
    const float f[4] = {v.x, v.y, v.z, v.w};
    const float* __restrict__ wr = wt + k4*4*DD;
    #pragma unroll
    for (int c = 0; c < DD; ++c) {
      float a = acc[c];
      #pragma unroll
      for (int j = 0; j < 4; ++j) a = fmaf(f[j], wr[j*DD + c], a);
      acc[c] = a;
    }
  }
}

__device__ __forceinline__ void gemv_reg(const float x[DD],
                                         const float* __restrict__ wt,
                                         float acc[DD]) {
  #pragma unroll 8
  for (int k = 0; k < DD; ++k) {
    const float fk = x[k];
    const float* __restrict__ wr = wt + k*DD;
    #pragma unroll
    for (int c = 0; c < DD; ++c) acc[c] = fmaf(fk, wr[c], acc[c]);
  }
}

__device__ __forceinline__ void store_row(float* __restrict__ o, const float acc[DD]) {
  float4* o4 = (float4*)o;
  #pragma unroll
  for (int i = 0; i < 16; ++i)
    o4[i] = make_float4(acc[4*i], acc[4*i+1], acc[4*i+2], acc[4*i+3]);
}

__device__ __forceinline__ void store_h_row(u16* __restrict__ o, const float acc[DD]) {
  uint4 s[8]; u32* sw = (u32*)s;
  #pragma unroll
  for (int i = 0; i < 32; ++i) sw[i] = pk2(acc[2*i], acc[2*i+1]);
  uint4* o4 = (uint4*)o;
  #pragma unroll
  for (int i = 0; i < 8; ++i) o4[i] = s[i];
}

__device__ __forceinline__ void addrow_h(const u16* __restrict__ r, float acc[DD]) {
  const uint4* r4 = (const uint4*)r;
  #pragma unroll
  for (int q = 0; q < 8; ++q) {
    const uint4 v = r4[q];
    const u32 w[4] = {v.x, v.y, v.z, v.w};
    #pragma unroll
    for (int h = 0; h < 4; ++h) {
      acc[q*8 + 2*h]     += bf2f((u16)(w[h] & 0xffffu));
      acc[q*8 + 2*h + 1] += bf2f((u16)(w[h] >> 16));
    }
  }
}

__global__ __launch_bounds__(256) void k_detect(const u32* __restrict__ idxw,
                                                int* __restrict__ flags) {
  __shared__ int cn;
  if (threadIdx.x == 0) cn = 0;
  __syncthreads();
  int c = 0;
  for (int k = 0; k < 16; ++k)
    c += (idxw[2*(threadIdx.x + k*256) + 1] != 0u) ? 1 : 0;
  atomicAdd(&cn, c);
  __syncthreads();
  if (threadIdx.x == 0) flags[0] = (cn == 0) ? 1 : 0;
}

__global__ __launch_bounds__(256) void k_hist(const u32* __restrict__ eidx,
                                              int* __restrict__ cntN,
                                              int* __restrict__ cntF,
                                              const int* __restrict__ flags) {
  const int e = blockIdx.x*256 + threadIdx.x;
  const int I64 = flags[0];
  const u32 src = I64 ? eidx[2*(size_t)e]        : eidx[e];
  const u32 dst = I64 ? eidx[2*((size_t)NE + e)] : eidx[(size_t)NE + e];
  atomicAdd(cntN + src, 1);
  atomicAdd(cntF + dst, 1);
}

__global__ __launch_bounds__(1024) void k_scan(const int* __restrict__ cnt,
                                               int* __restrict__ sta) {
  const int base = blockIdx.x * 50000;
  const int t = threadIdx.x;
  __shared__ int part[1024];
  int local[49];
  int s = 0;
  const int start = t * 49;
  #pragma unroll
  for (int j = 0; j < 49; ++j) {
    const int idx = start + j;
    const int v = (idx < 50000) ? cnt[base + idx] : 0;
    local[j] = s;
    s += v;
  }
  part[t] = s;
  __syncthreads();
  for (int off = 1; off < 1024; off <<= 1) {
    int v = 0;
    if (t >= off) v = part[t - off];
    __syncthreads();
    if (t >= off) part[t] += v;
    __syncthreads();
  }
  const int bv = (t > 0) ? part[t - 1] : 0;
  #pragma unroll
  for (int j = 0; j < 49; ++j) {
    const int idx = start + j;
    if (idx < 50000) sta[base + idx] = bv + local[j];
  }
}

__global__ __launch_bounds__(256) void k_fill(const u32* __restrict__ eidx,
                                              int* __restrict__ staN,
                                              int* __restrict__ staF,
                                              int* __restrict__ othN,
                                              int* __restrict__ othF,
                                              int* __restrict__ posN,
                                              int* __restrict__ posF,
                                              const int* __restrict__ flags) {
  const int e = blockIdx.x*256 + threadIdx.x;
  const int I64 = flags[0];
  const u32 src = I64 ? eidx[2*(size_t)e]        : eidx[e];
  const u32 dst = I64 ? eidx[2*((size_t)NE + e)] : eidx[(size_t)NE + e];
  const int pN = atomicAdd(staN + src, 1);
  const int pF = atomicAdd(staF + dst, 1);
  othN[pN] = (int)dst;
  othF[pF] = (int)src;
  posN[e] = pN;
  posF[e] = pF;
}

// pack P1 (64x64 fp32, row-major K x N) into 8 MFMA B-fragments of bf16:
// frag f = kk*4+nt; value at Bpk[(f*64+lane)*8+j] = P1[(kk*32+(lane>>4)*8+j)*64 + nt*16+(lane&15)]
__global__ __launch_bounds__(256) void k_bpack(const float* __restrict__ Wsrc,
                                               u16* __restrict__ Bpk) {
  const int v = blockIdx.x*256 + threadIdx.x;   // 0..4095
  const int f = v >> 9, rem = v & 511;
  const int lane = rem >> 3, j = rem & 7;
  const int kk = f >> 2, nt = f & 3;
  const int k = kk*32 + (lane>>4)*8 + j;
  const int col = nt*16 + (lane&15);
  Bpk[v] = f2bf(Wsrc[k*64 + col]);
}

// proj[row] (bf16) = emb[row] @ wt    (round-10 proven)
__global__ __launch_bounds__(256) void k_proj(const float* __restrict__ emb,
                                              const float* __restrict__ wt,
                                              u16* __restrict__ outp) {
  const int row = blockIdx.x*256 + threadIdx.x;
  if (row >= 50000) return;
  float acc[DD];
  #pragma unroll
  for (int c = 0; c < DD; ++c) acc[c] = 0.f;
  gemv_f32(emb + (size_t)row*DD, wt, acc);
  store_h_row(outp + (size_t)row*DD, acc);
}

// MFMA ep: per block 64 edges x 64 cols = X(64x64) @ P1 + bP, bf16 rows scattered
// to CSR slots posN/posF. A staged in swizzled LDS; C transposed through same LDS.
__global__ __launch_bounds__(256) void k_epm(const float* __restrict__ eemb,
                                             const u16* __restrict__ Bpk,
                                             const float* __restrict__ bP,
                                             const int* __restrict__ posN,
                                             const int* __restrict__ posF,
                                             u16* __restrict__ epN,
                                             u16* __restrict__ epF) {
  __shared__ u16 lds[4096];   // 64 rows x 128B, XOR-swizzled
  const int t = threadIdx.x;
  const int e0 = blockIdx.x * 64;
  // stage: 4 coalesced float4 loads -> bf16 -> LDS
  #pragma unroll
  for (int i = 0; i < 4; ++i) {
    const int g = i*256 + t;                 // float4 index in 64x64 tile
    const float4 v = ((const float4*)(eemb + (size_t)e0*DD))[g];
    const int row = g >> 4;
    const int b   = (g & 15) * 8;            // byte offset of 4 bf16
    *(uint2*)((char*)lds + LDSW(row, b)) = make_uint2(pk2(v.x, v.y), pk2(v.z, v.w));
  }
  __syncthreads();
  const int w = t >> 6, l = t & 63;
  // B fragments (coalesced, L1-resident after first wave)
  bf16x8 bf[8];
  #pragma unroll
  for (int f = 0; f < 8; ++f)
    bf[f] = *(const bf16x8*)(Bpk + (f*64 + l)*8);
  // bias into accumulators (bias depends only on col = nt*16 + (l&15))
  f32x4 acc[4];
  #pragma unroll
  for (int nt = 0; nt < 4; ++nt) {
    const float b = bP[nt*16 + (l&15)];
    acc[nt] = (f32x4){b, b, b, b};
  }
  // A fragments: row = w*16 + (l&15), k-block = (l>>4)*8 (+32 for kk=1)
  const int arow = w*16 + (l&15);
  const bf16x8 a0 = *(const bf16x8*)((char*)lds + LDSW(arow, (l>>4)*16));
  const bf16x8 a1 = *(const bf16x8*)((char*)lds + LDSW(arow, 64 + (l>>4)*16));
  #pragma unroll
  for (int nt = 0; nt < 4; ++nt) {
    acc[nt] = __builtin_amdgcn_mfma_f32_16x16x32_bf16(a0, bf[nt],     acc[nt], 0, 0, 0);
    acc[nt] = __builtin_amdgcn_mfma_f32_16x16x32_bf16(a1, bf[4 + nt], acc[nt], 0, 0, 0);
  }
  // C -> LDS transpose (wave-local rows; LDS ops in-order per wave, no barrier)
  #pragma unroll
  for (int nt = 0; nt < 4; ++nt) {
    #pragma unroll
    for (int r = 0; r < 4; ++r) {
      const int row = w*16 + (l>>4)*4 + r;
      const int col = nt*16 + (l&15);
      *(u16*)((char*)lds + LDSW(row, col*2)) = f2bf(acc[nt][r]);
    }
  }
  // readback contiguous rows, scatter to CSR slots
  const int lr = l >> 2, seg = l & 3;
  const int row = w*16 + lr;
  const int e = e0 + row;
  const uint4 c0 = *(const uint4*)((char*)lds + LDSW(row, seg*32));
  const uint4 c1 = *(const uint4*)((char*)lds + LDSW(row, seg*32 + 16));
  const int pN = posN[e];
  *(uint4*)(epN + (size_t)pN*DD + seg*16)     = c0;
  *(uint4*)(epN + (size_t)pN*DD + seg*16 + 8) = c1;
  const int pF = posF[e];
  *(uint4*)(epF + (size_t)pF*DD + seg*16)     = c0;
  *(uint4*)(epF + (size_t)pF*DD + seg*16 + 8) = c1;
}

// one wave per node: msg[n] = SUM over CSR range of relu(eps[i] + proj[oth[i]])
__global__ __launch_bounds__(256) void k_gather2(const int* __restrict__ sta,
                                                 const int* __restrict__ cnt,
                                                 const int* __restrict__ oth,
                                                 const u16* __restrict__ eps,
                                                 const u16* __restrict__ proj,
                                                 float* __restrict__ msg) {
  const int n = blockIdx.x*4 + (threadIdx.x >> 6);
  const int lane = threadIdx.x & 63;
  const int end = sta[n];
  const int c = cnt[n];
  float acc = 0.f;
  #pragma unroll 4
  for (int i = end - c; i < end; ++i) {
    const int o = oth[i];
    acc += fmaxf(bf2f(eps[(size_t)i*DD + lane]) + bf2f(proj[(size_t)o*DD + lane]), 0.f);
  }
  msg[(size_t)n*DD + lane] = acc;
}

// out = emb@Q0 + mean_msg@Q1 + bQ ; then (out@Wseg) as bf16 in-place over msg row
__global__ __launch_bounds__(256) void k_upd(const float* __restrict__ emb,
                                             float* msgp,
                                             const int* __restrict__ cnt,
                                             const float* __restrict__ Q,
                                             const float* __restrict__ bQ,
                                             const float* __restrict__ Wseg,
                                             float* __restrict__ outp) {
  const int row = blockIdx.x*256 + threadIdx.x;
  if (row >= 50000) return;
  const float inv = 1.f / fmaxf((float)cnt[row], 1.f);
  float m[DD];
  {
    const float4* mp = (const float4*)(msgp + (size_t)row*DD);
    #pragma unroll
    for (int i = 0; i < 16; ++i) {
      const float4 v = mp[i];
      m[4*i] = v.x*inv; m[4*i+1] = v.y*inv; m[4*i+2] = v.z*inv; m[4*i+3] = v.w*inv;
    }
  }
  float acc[DD];
  #pragma unroll
  for (int c = 0; c < DD; ++c) acc[c] = bQ[c];
  gemv_f32(emb + (size_t)row*DD, Q, acc);
  gemv_reg(m, Q + 64*DD, acc);
  store_row(outp + (size_t)row*DD, acc);

  float acc2[DD];
  #pragma unroll
  for (int c = 0; c < DD; ++c) acc2[c] = 0.f;
  gemv_reg(acc, Wseg, acc2);
  store_h_row((u16*)(msgp + (size_t)row*DD), acc2);
}

// fused edge_out = eemb@W0 + bW + NOw[src] + FOw[dst]  (round-10 proven)
__global__ __launch_bounds__(256) void k_eout(const float* __restrict__ eemb,
                                              const u32* __restrict__ eidx,
                                              const float* __restrict__ W,
                                              const float* __restrict__ bW,
                                              const u16* __restrict__ NOw,
                                              const u16* __restrict__ FOw,
                                              float* __restrict__ outp,
                                              const int* __restrict__ flags) {
  const int e = blockIdx.x*256 + threadIdx.x;
  const int I64 = flags[0];
  const u32 src = I64 ? eidx[2*(size_t)e]        : eidx[e];
  const u32 dst = I64 ? eidx[2*((size_t)NE + e)] : eidx[(size_t)NE + e];
  float acc[DD];
  #pragma unroll
  for (int c = 0; c < DD; ++c) acc[c] = bW[c];
  gemv_f32(eemb + (size_t)e*DD, W, acc);
  addrow_h(NOw + (size_t)src*128, acc);
  addrow_h(FOw + (size_t)dst*128, acc);
  store_row(outp + (size_t)e*DD, acc);
}

extern "C" void kernel_launch(void* const* d_in, const int* in_sizes, int n_in,
                              void* d_out, int out_size, void* d_ws, size_t ws_size,
                              hipStream_t stream) {
  if (ws_size < (size_t)WS_FLOATS * 4) return;
  const float* node = (const float*)d_in[0];
  const float* eemb = (const float*)d_in[1];
  const float* feat = (const float*)d_in[2];
  const u32*   eidx = (const u32*)d_in[3];
  const float* P  = (const float*)d_in[4];
  const float* bP = (const float*)d_in[5];
  const float* Q  = (const float*)d_in[6];
  const float* bQ = (const float*)d_in[7];
  const float* W  = (const float*)d_in[8];
  const float* bW = (const float*)d_in[9];
  float* wsf = (float*)d_ws;
  int*   wsi = (int*)d_ws;
  float* out = (float*)d_out;

  u16* Fp_h = (u16*)out;
  u16* epN_h = (u16*)(out + (size_t)ND*DD);
  u16* epF_h = epN_h + (size_t)NE*DD;
  u16* Np_h = (u16*)(out + (size_t)(ND + NE)*DD);
  float* msgN = wsf + OFF_MSGN;
  float* msgF = wsf + OFF_MSGF;
  int* posN = (int*)(wsf + OFF_MSGN);   // overlays msgN start; dead after k_epm
  int* posF = posN + NE;
  u16* Bpk = (u16*)(wsf + OFF_BPK);

  hipMemsetAsync((void*)(wsi + OFF_CNTN), 0, (size_t)100000 * 4, stream);
  k_detect<<<1, 256, 0, stream>>>(eidx, wsi + OFF_FLAGS);
  k_bpack<<<16, 256, 0, stream>>>(P + 64*DD, Bpk);
  k_hist<<<EBLK, 256, 0, stream>>>(eidx, wsi + OFF_CNTN, wsi + OFF_CNTF, wsi + OFF_FLAGS);
  k_scan<<<2, 1024, 0, stream>>>(wsi + OFF_CNTN, wsi + OFF_STAN);
  k_fill<<<EBLK, 256, 0, stream>>>(eidx, wsi + OFF_STAN, wsi + OFF_STAF,
                                   wsi + OFF_OTHN, wsi + OFF_OTHF,
                                   posN, posF, wsi + OFF_FLAGS);
  k_proj<<<NBLK, 256, 0, stream>>>(feat, P, Fp_h);
  k_proj<<<NBLK, 256, 0, stream>>>(node, P, Np_h);
  k_epm<<<12500, 256, 0, stream>>>(eemb, Bpk, bP, posN, posF, epN_h, epF_h);
  k_gather2<<<12500, 256, 0, stream>>>(wsi + OFF_STAN, wsi + OFF_CNTN,
                                       wsi + OFF_OTHN, epN_h, Fp_h, msgN);
  k_gather2<<<12500, 256, 0, stream>>>(wsi + OFF_STAF, wsi + OFF_CNTF,
                                       wsi + OFF_OTHF, epF_h, Np_h, msgF);
  k_upd<<<NBLK, 256, 0, stream>>>(feat, msgF, wsi + OFF_CNTF, Q, bQ, W + 128*DD,
                                  out + (size_t)(ND + NE)*DD);
  k_upd<<<NBLK, 256, 0, stream>>>(node, msgN, wsi + OFF_CNTN, Q, bQ, W + 64*DD, out);
  k_eout<<<EBLK, 256, 0, stream>>>(eemb, eidx, W, bW,
                                   (const u16*)msgN, (const u16*)msgF,
                                   out + (size_t)ND*DD, wsi + OFF_FLAGS);
}

// Round 13
// 862.214 us; speedup vs baseline: 1.7224x; 1.0784x over previous
//
#include <hip/hip_runtime.h>

typedef unsigned int u32;
typedef unsigned short u16;
using bf16x8 = __attribute__((ext_vector_type(8))) short;
using f32x4  = __attribute__((ext_vector_type(4))) float;

#define ND 50000
#define NF 50000
#define NE 800000
#define DD 64
#define NBLK 196   // ceil(50000/256)
#define EBLK 3125  // 800000/256

// ---- ws float-index layout ----
#define OFF_FLAGS 0                        // [0] = idx-is-int64
#define OFF_CNTN  64
#define OFF_CNTF  (OFF_CNTN + 50000)
#define OFF_STAN  (OFF_CNTF + 50000)
#define OFF_STAF  (OFF_STAN + 50000)
#define OFF_OTHN  (OFF_STAF + 50000)
#define OFF_OTHF  (OFF_OTHN + 800000)
#define OFF_MSGN  (OFF_OTHF + 800000)
#define OFF_MSGF  (OFF_MSGN + 3200000)
#define OFF_BPK   (OFF_MSGF + 3200000)     // 4096 floats: 8192 bf16 B-fragments (P1 | W0)
#define WS_FLOATS (OFF_BPK + 4096)

// d_out overlays (strictly ordered across kernel boundaries) — as round 10/12.

__device__ __forceinline__ u16 f2bf(float x){ union{u32 u;float f;}v; v.f=x; u32 r=v.u+0x7fffu+((v.u>>16)&1u); return (u16)(r>>16); }
__device__ __forceinline__ float bf2f(u16 h){ union{u32 u;float f;}v; v.u=((u32)h)<<16; return v.f; }
__device__ __forceinline__ u32 pk2(float a,float b){ return (u32)f2bf(a) | ((u32)f2bf(b)<<16); }

// swizzled LDS byte offset for 64x128B tile (guide G4 attn pattern)
#define LDSW(row, b) ((row)*128 + ((b) ^ (((row)&7)<<4)))

__device__ __forceinline__ void gemv_f32(const float* __restrict__ x,
                                         const float* __restrict__ wt,
                                         float acc[DD]) {
  #pragma unroll 4
  for (int k4 = 0; k4 < 16; ++k4) {
    const float4 v = *(const float4*)(x + k4*4);
    const float f[4] = {v.x, v.y, v.z, v.w};
    const float* __restrict__ wr = wt + k4*4*DD;
    #pragma unroll
    for (int c = 0; c < DD; ++c) {
      float a = acc[c];
      #pragma unroll
      for (int j = 0; j < 4; ++j) a = fmaf(f[j], wr[j*DD + c], a);
      acc[c] = a;
    }
  }
}

__device__ __forceinline__ void gemv_reg(const float x[DD],
                                         const float* __restrict__ wt,
                                         float acc[DD]) {
  #pragma unroll 8
  for (int k = 0; k < DD; ++k) {
    const float fk = x[k];
    const float* __restrict__ wr = wt + k*DD;
    #pragma unroll
    for (int c = 0; c < DD; ++c) acc[c] = fmaf(fk, wr[c], acc[c]);
  }
}

__device__ __forceinline__ void store_row(float* __restrict__ o, const float acc[DD]) {
  float4* o4 = (float4*)o;
  #pragma unroll
  for (int i = 0; i < 16; ++i)
    o4[i] = make_float4(acc[4*i], acc[4*i+1], acc[4*i+2], acc[4*i+3]);
}

__device__ __forceinline__ void store_h_row(u16* __restrict__ o, const float acc[DD]) {
  uint4 s[8]; u32* sw = (u32*)s;
  #pragma unroll
  for (int i = 0; i < 32; ++i) sw[i] = pk2(acc[2*i], acc[2*i+1]);
  uint4* o4 = (uint4*)o;
  #pragma unroll
  for (int i = 0; i < 8; ++i) o4[i] = s[i];
}

// r[0..7] = bf16x8 from uint4
__device__ __forceinline__ void set8(const uint4 v, float* r) {
  r[0]=bf2f((u16)(v.x&0xffffu)); r[1]=bf2f((u16)(v.x>>16));
  r[2]=bf2f((u16)(v.y&0xffffu)); r[3]=bf2f((u16)(v.y>>16));
  r[4]=bf2f((u16)(v.z&0xffffu)); r[5]=bf2f((u16)(v.z>>16));
  r[6]=bf2f((u16)(v.w&0xffffu)); r[7]=bf2f((u16)(v.w>>16));
}
__device__ __forceinline__ void add8(const uint4 v, float* r) {
  r[0]+=bf2f((u16)(v.x&0xffffu)); r[1]+=bf2f((u16)(v.x>>16));
  r[2]+=bf2f((u16)(v.y&0xffffu)); r[3]+=bf2f((u16)(v.y>>16));
  r[4]+=bf2f((u16)(v.z&0xffffu)); r[5]+=bf2f((u16)(v.z>>16));
  r[6]+=bf2f((u16)(v.w&0xffffu)); r[7]+=bf2f((u16)(v.w>>16));
}

__global__ __launch_bounds__(256) void k_detect(const u32* __restrict__ idxw,
                                                int* __restrict__ flags) {
  __shared__ int cn;
  if (threadIdx.x == 0) cn = 0;
  __syncthreads();
  int c = 0;
  for (int k = 0; k < 16; ++k)
    c += (idxw[2*(threadIdx.x + k*256) + 1] != 0u) ? 1 : 0;
  atomicAdd(&cn, c);
  __syncthreads();
  if (threadIdx.x == 0) flags[0] = (cn == 0) ? 1 : 0;
}

__global__ __launch_bounds__(256) void k_hist(const u32* __restrict__ eidx,
                                              int* __restrict__ cntN,
                                              int* __restrict__ cntF,
                                              const int* __restrict__ flags) {
  const int e = blockIdx.x*256 + threadIdx.x;
  const int I64 = flags[0];
  const u32 src = I64 ? eidx[2*(size_t)e]        : eidx[e];
  const u32 dst = I64 ? eidx[2*((size_t)NE + e)] : eidx[(size_t)NE + e];
  atomicAdd(cntN + src, 1);
  atomicAdd(cntF + dst, 1);
}

__global__ __launch_bounds__(1024) void k_scan(const int* __restrict__ cnt,
                                               int* __restrict__ sta) {
  const int base = blockIdx.x * 50000;
  const int t = threadIdx.x;
  __shared__ int part[1024];
  int local[49];
  int s = 0;
  const int start = t * 49;
  #pragma unroll
  for (int j = 0; j < 49; ++j) {
    const int idx = start + j;
    const int v = (idx < 50000) ? cnt[base + idx] : 0;
    local[j] = s;
    s += v;
  }
  part[t] = s;
  __syncthreads();
  for (int off = 1; off < 1024; off <<= 1) {
    int v = 0;
    if (t >= off) v = part[t - off];
    __syncthreads();
    if (t >= off) part[t] += v;
    __syncthreads();
  }
  const int bv = (t > 0) ? part[t - 1] : 0;
  #pragma unroll
  for (int j = 0; j < 49; ++j) {
    const int idx = start + j;
    if (idx < 50000) sta[base + idx] = bv + local[j];
  }
}

__global__ __launch_bounds__(256) void k_fill(const u32* __restrict__ eidx,
                                              int* __restrict__ staN,
                                              int* __restrict__ staF,
                                              int* __restrict__ othN,
                                              int* __restrict__ othF,
                                              int* __restrict__ posN,
                                              int* __restrict__ posF,
                                              const int* __restrict__ flags) {
  const int e = blockIdx.x*256 + threadIdx.x;
  const int I64 = flags[0];
  const u32 src = I64 ? eidx[2*(size_t)e]        : eidx[e];
  const u32 dst = I64 ? eidx[2*((size_t)NE + e)] : eidx[(size_t)NE + e];
  const int pN = atomicAdd(staN + src, 1);
  const int pF = atomicAdd(staF + dst, 1);
  othN[pN] = (int)dst;
  othF[pF] = (int)src;
  posN[e] = pN;
  posF[e] = pF;
}

// pack P1 and W0 (each 64x64 fp32 K x N) into MFMA B-fragments (bf16):
// half h: frag f = kk*4+nt; Bpk[h*4096 + (f*64+lane)*8+j] = S[(kk*32+(lane>>4)*8+j)*64 + nt*16+(lane&15)]
__global__ __launch_bounds__(256) void k_bpack2(const float* __restrict__ S0,
                                                const float* __restrict__ S1,
                                                u16* __restrict__ Bpk) {
  const int v = blockIdx.x*256 + threadIdx.x;   // 0..8191
  const int half = v >> 12;
  const int vv = v & 4095;
  const int f = vv >> 9, rem = vv & 511;
  const int lane = rem >> 3, j = rem & 7;
  const int kk = f >> 2, nt = f & 3;
  const int k = kk*32 + (lane>>4)*8 + j;
  const int col = nt*16 + (lane&15);
  const float* __restrict__ S = half ? S1 : S0;
  Bpk[v] = f2bf(S[k*64 + col]);
}

// proj[row] (bf16) = emb[row] @ wt    (round-10 proven)
__global__ __launch_bounds__(256) void k_proj(const float* __restrict__ emb,
                                              const float* __restrict__ wt,
                                              u16* __restrict__ outp) {
  const int row = blockIdx.x*256 + threadIdx.x;
  if (row >= 50000) return;
  float acc[DD];
  #pragma unroll
  for (int c = 0; c < DD; ++c) acc[c] = 0.f;
  gemv_f32(emb + (size_t)row*DD, wt, acc);
  store_h_row(outp + (size_t)row*DD, acc);
}

// MFMA ep: per block 64 edges x 64 cols = X(64x64) @ P1 + bP, bf16 rows scattered
// to CSR slots posN/posF. (round-12 proven)
__global__ __launch_bounds__(256) void k_epm(const float* __restrict__ eemb,
                                             const u16* __restrict__ Bpk,
                                             const float* __restrict__ bP,
                                             const int* __restrict__ posN,
                                             const int* __restrict__ posF,
                                             u16* __restrict__ epN,
                                             u16* __restrict__ epF) {
  __shared__ u16 lds[4096];   // 64 rows x 128B, XOR-swizzled
  const int t = threadIdx.x;
  const int e0 = blockIdx.x * 64;
  #pragma unroll
  for (int i = 0; i < 4; ++i) {
    const int g = i*256 + t;
    const float4 v = ((const float4*)(eemb + (size_t)e0*DD))[g];
    const int row = g >> 4;
    const int b   = (g & 15) * 8;
    *(uint2*)((char*)lds + LDSW(row, b)) = make_uint2(pk2(v.x, v.y), pk2(v.z, v.w));
  }
  __syncthreads();
  const int w = t >> 6, l = t & 63;
  bf16x8 bf[8];
  #pragma unroll
  for (int f = 0; f < 8; ++f)
    bf[f] = *(const bf16x8*)(Bpk + (f*64 + l)*8);
  f32x4 acc[4];
  #pragma unroll
  for (int nt = 0; nt < 4; ++nt) {
    const float b = bP[nt*16 + (l&15)];
    acc[nt] = (f32x4){b, b, b, b};
  }
  const int arow = w*16 + (l&15);
  const bf16x8 a0 = *(const bf16x8*)((char*)lds + LDSW(arow, (l>>4)*16));
  const bf16x8 a1 = *(const bf16x8*)((char*)lds + LDSW(arow, 64 + (l>>4)*16));
  #pragma unroll
  for (int nt = 0; nt < 4; ++nt) {
    acc[nt] = __builtin_amdgcn_mfma_f32_16x16x32_bf16(a0, bf[nt],     acc[nt], 0, 0, 0);
    acc[nt] = __builtin_amdgcn_mfma_f32_16x16x32_bf16(a1, bf[4 + nt], acc[nt], 0, 0, 0);
  }
  #pragma unroll
  for (int nt = 0; nt < 4; ++nt) {
    #pragma unroll
    for (int r = 0; r < 4; ++r) {
      const int row = w*16 + (l>>4)*4 + r;
      const int col = nt*16 + (l&15);
      *(u16*)((char*)lds + LDSW(row, col*2)) = f2bf(acc[nt][r]);
    }
  }
  const int lr = l >> 2, seg = l & 3;
  const int row = w*16 + lr;
  const int e = e0 + row;
  const uint4 c0 = *(const uint4*)((char*)lds + LDSW(row, seg*32));
  const uint4 c1 = *(const uint4*)((char*)lds + LDSW(row, seg*32 + 16));
  const int pN = posN[e];
  *(uint4*)(epN + (size_t)pN*DD + seg*16)     = c0;
  *(uint4*)(epN + (size_t)pN*DD + seg*16 + 8) = c1;
  const int pF = posF[e];
  *(uint4*)(epF + (size_t)pF*DD + seg*16)     = c0;
  *(uint4*)(epF + (size_t)pF*DD + seg*16 + 8) = c1;
}

// MFMA edge_out: X(64x64)@W0 + bW (matmul via MFMA, C transposed through LDS),
// then per-lane quarter-row gather-adds of NOw[src]/FOw[dst], fp32 store.
__global__ __launch_bounds__(256) void k_eoutm(const float* __restrict__ eemb,
                                               const u32* __restrict__ eidx,
                                               const u16* __restrict__ BpkW,  // W0 fragments
                                               const float* __restrict__ bW,
                                               const u16* __restrict__ NOw,   // stride 128 u16/row
                                               const u16* __restrict__ FOw,
                                               float* __restrict__ outp,
                                               const int* __restrict__ flags) {
  __shared__ u16 lds[4096];
  const int t = threadIdx.x;
  const int e0 = blockIdx.x * 64;
  #pragma unroll
  for (int i = 0; i < 4; ++i) {
    const int g = i*256 + t;
    const float4 v = ((const float4*)(eemb + (size_t)e0*DD))[g];
    const int row = g >> 4;
    const int b   = (g & 15) * 8;
    *(uint2*)((char*)lds + LDSW(row, b)) = make_uint2(pk2(v.x, v.y), pk2(v.z, v.w));
  }
  __syncthreads();
  const int w = t >> 6, l = t & 63;
  bf16x8 bf[8];
  #pragma unroll
  for (int f = 0; f < 8; ++f)
    bf[f] = *(const bf16x8*)(BpkW + (f*64 + l)*8);
  f32x4 acc[4];
  #pragma unroll
  for (int nt = 0; nt < 4; ++nt) {
    const float b = bW[nt*16 + (l&15)];
    acc[nt] = (f32x4){b, b, b, b};
  }
  const int arow = w*16 + (l&15);
  const bf16x8 a0 = *(const bf16x8*)((char*)lds + LDSW(arow, (l>>4)*16));
  const bf16x8 a1 = *(const bf16x8*)((char*)lds + LDSW(arow, 64 + (l>>4)*16));
  #pragma unroll
  for (int nt = 0; nt < 4; ++nt) {
    acc[nt] = __builtin_amdgcn_mfma_f32_16x16x32_bf16(a0, bf[nt],     acc[nt], 0, 0, 0);
    acc[nt] = __builtin_amdgcn_mfma_f32_16x16x32_bf16(a1, bf[4 + nt], acc[nt], 0, 0, 0);
  }
  // C -> LDS bf16 transpose (wave-local rows)
  #pragma unroll
  for (int nt = 0; nt < 4; ++nt) {
    #pragma unroll
    for (int r = 0; r < 4; ++r) {
      const int row = w*16 + (l>>4)*4 + r;
      const int col = nt*16 + (l&15);
      *(u16*)((char*)lds + LDSW(row, col*2)) = f2bf(acc[nt][r]);
    }
  }
  // epilogue: quarter-row per lane; gather-add NOw[src], FOw[dst]; fp32 store
  const int lr = l >> 2, seg = l & 3;
  const int row = w*16 + lr;
  const int e = e0 + row;
  const int I64 = flags[0];
  const u32 src = I64 ? eidx[2*(size_t)e]        : eidx[e];
  const u32 dst = I64 ? eidx[2*((size_t)NE + e)] : eidx[(size_t)NE + e];
  const uint4 c0 = *(const uint4*)((char*)lds + LDSW(row, seg*32));
  const uint4 c1 = *(const uint4*)((char*)lds + LDSW(row, seg*32 + 16));
  float r[16];
  set8(c0, r); set8(c1, r + 8);
  add8(*(const uint4*)(NOw + (size_t)src*128 + seg*16),     r);
  add8(*(const uint4*)(NOw + (size_t)src*128 + seg*16 + 8), r + 8);
  add8(*(const uint4*)(FOw + (size_t)dst*128 + seg*16),     r);
  add8(*(const uint4*)(FOw + (size_t)dst*128 + seg*16 + 8), r + 8);
  float4* o4 = (float4*)(outp + (size_t)e*DD + seg*16);
  #pragma unroll
  for (int i = 0; i < 4; ++i)
    o4[i] = make_float4(r[4*i], r[4*i+1], r[4*i+2], r[4*i+3]);
}

// one wave per node: msg[n] = SUM over CSR range of relu(eps[i] + proj[oth[i]])
__global__ __launch_bounds__(256) void k_gather2(const int* __restrict__ sta,
                                                 const int* __restrict__ cnt,
                                                 const int* __restrict__ oth,
                                                 const u16* __restrict__ eps,
                                                 const u16* __restrict__ proj,
                                                 float* __restrict__ msg) {
  const int n = blockIdx.x*4 + (threadIdx.x >> 6);
  const int lane = threadIdx.x & 63;
  const int end = sta[n];
  const int c = cnt[n];
  float acc = 0.f;
  #pragma unroll 4
  for (int i = end - c; i < end; ++i) {
    const int o = oth[i];
    acc += fmaxf(bf2f(eps[(size_t)i*DD + lane]) + bf2f(proj[(size_t)o*DD + lane]), 0.f);
  }
  msg[(size_t)n*DD + lane] = acc;
}

// out = emb@Q0 + mean_msg@Q1 + bQ ; then (out@Wseg) as bf16 in-place over msg row
__global__ __launch_bounds__(256) void k_upd(const float* __restrict__ emb,
                                             float* msgp,
                                             const int* __restrict__ cnt,
                                             const float* __restrict__ Q,
                                             const float* __restrict__ bQ,
                                             const float* __restrict__ Wseg,
                                             float* __restrict__ outp) {
  const int row = blockIdx.x*256 + threadIdx.x;
  if (row >= 50000) return;
  const float inv = 1.f / fmaxf((float)cnt[row], 1.f);
  float m[DD];
  {
    const float4* mp = (const float4*)(msgp + (size_t)row*DD);
    #pragma unroll
    for (int i = 0; i < 16; ++i) {
      const float4 v = mp[i];
      m[4*i] = v.x*inv; m[4*i+1] = v.y*inv; m[4*i+2] = v.z*inv; m[4*i+3] = v.w*inv;
    }
  }
  float acc[DD];
  #pragma unroll
  for (int c = 0; c < DD; ++c) acc[c] = bQ[c];
  gemv_f32(emb + (size_t)row*DD, Q, acc);
  gemv_reg(m, Q + 64*DD, acc);
  store_row(outp + (size_t)row*DD, acc);

  float acc2[DD];
  #pragma unroll
  for (int c = 0; c < DD; ++c) acc2[c] = 0.f;
  gemv_reg(acc, Wseg, acc2);
  store_h_row((u16*)(msgp + (size_t)row*DD), acc2);
}

extern "C" void kernel_launch(void* const* d_in, const int* in_sizes, int n_in,
                              void* d_out, int out_size, void* d_ws, size_t ws_size,
                              hipStream_t stream) {
  if (ws_size < (size_t)WS_FLOATS * 4) return;
  const float* node = (const float*)d_in[0];
  const float* eemb = (const float*)d_in[1];
  const float* feat = (const float*)d_in[2];
  const u32*   eidx = (const u32*)d_in[3];
  const float* P  = (const float*)d_in[4];
  const float* bP = (const float*)d_in[5];
  const float* Q  = (const float*)d_in[6];
  const float* bQ = (const float*)d_in[7];
  const float* W  = (const float*)d_in[8];
  const float* bW = (const float*)d_in[9];
  float* wsf = (float*)d_ws;
  int*   wsi = (int*)d_ws;
  float* out = (float*)d_out;

  u16* Fp_h = (u16*)out;
  u16* epN_h = (u16*)(out + (size_t)ND*DD);
  u16* epF_h = epN_h + (size_t)NE*DD;
  u16* Np_h = (u16*)(out + (size_t)(ND + NE)*DD);
  float* msgN = wsf + OFF_MSGN;
  float* msgF = wsf + OFF_MSGF;
  int* posN = (int*)(wsf + OFF_MSGN);   // overlays msgN start; dead after k_epm
  int* posF = posN + NE;
  u16* Bpk = (u16*)(wsf + OFF_BPK);     // [0,4096): P1 frags; [4096,8192): W0 frags

  hipMemsetAsync((void*)(wsi + OFF_CNTN), 0, (size_t)100000 * 4, stream);
  k_detect<<<1, 256, 0, stream>>>(eidx, wsi + OFF_FLAGS);
  k_bpack2<<<32, 256, 0, stream>>>(P + 64*DD, W, Bpk);
  k_hist<<<EBLK, 256, 0, stream>>>(eidx, wsi + OFF_CNTN, wsi + OFF_CNTF, wsi + OFF_FLAGS);
  k_scan<<<2, 1024, 0, stream>>>(wsi + OFF_CNTN, wsi + OFF_STAN);
  k_fill<<<EBLK, 256, 0, stream>>>(eidx, wsi + OFF_STAN, wsi + OFF_STAF,
                                   wsi + OFF_OTHN, wsi + OFF_OTHF,
                                   posN, posF, wsi + OFF_FLAGS);
  k_proj<<<NBLK, 256, 0, stream>>>(feat, P, Fp_h);
  k_proj<<<NBLK, 256, 0, stream>>>(node, P, Np_h);
  k_epm<<<12500, 256, 0, stream>>>(eemb, Bpk, bP, posN, posF, epN_h, epF_h);
  k_gather2<<<12500, 256, 0, stream>>>(wsi + OFF_STAN, wsi + OFF_CNTN,
                                       wsi + OFF_OTHN, epN_h, Fp_h, msgN);
  k_gather2<<<12500, 256, 0, stream>>>(wsi + OFF_STAF, wsi + OFF_CNTF,
                                       wsi + OFF_OTHF, epF_h, Np_h, msgF);
  k_upd<<<NBLK, 256, 0, stream>>>(feat, msgF, wsi + OFF_CNTF, Q, bQ, W + 128*DD,
                                  out + (size_t)(ND + NE)*DD);
  k_upd<<<NBLK, 256, 0, stream>>>(node, msgN, wsi + OFF_CNTN, Q, bQ, W + 64*DD, out);
  k_eoutm<<<12500, 256, 0, stream>>>(eemb, eidx, Bpk + 4096, bW,
                                     (const u16*)msgN, (const u16*)msgF,
                                     out + (size_t)ND*DD, wsi + OFF_FLAGS);
}

// Round 14
// 648.423 us; speedup vs baseline: 2.2903x; 1.3297x over previous
//
#include <hip/hip_runtime.h>

typedef unsigned int u32;
typedef unsigned short u16;
using bf16x8 = __attribute__((ext_vector_type(8))) short;
using f32x4  = __attribute__((ext_vector_type(4))) float;

#define ND 50000
#define NF 50000
#define NE 800000
#define DD 64
#define NBLK 196   // ceil(50000/256)
#define EBLK 3125  // 800000/256
#define UBLK 782   // ceil(50000/64)

// ---- ws float-index layout ----
#define OFF_FLAGS 0                        // [0] = idx-is-int64
#define OFF_CNTN  64
#define OFF_CNTF  (OFF_CNTN + 50000)
#define OFF_STAN  (OFF_CNTF + 50000)
#define OFF_STAF  (OFF_STAN + 50000)
#define OFF_OTHN  (OFF_STAF + 50000)
#define OFF_OTHF  (OFF_OTHN + 800000)
#define OFF_MSGN  (OFF_OTHF + 800000)
#define OFF_MSGF  (OFF_MSGN + 3200000)
#define OFF_BPK   (OFF_MSGF + 3200000)     // 12288 floats: 6*4096 bf16 B-frags
                                           // [P1 | W0 | Q0 | Q1 | W1 | W2]
#define WS_FLOATS (OFF_BPK + 12288)

__device__ __forceinline__ u16 f2bf(float x){ union{u32 u;float f;}v; v.f=x; u32 r=v.u+0x7fffu+((v.u>>16)&1u); return (u16)(r>>16); }
__device__ __forceinline__ float bf2f(u16 h){ union{u32 u;float f;}v; v.u=((u32)h)<<16; return v.f; }
__device__ __forceinline__ u32 pk2(float a,float b){ return (u32)f2bf(a) | ((u32)f2bf(b)<<16); }

// swizzled LDS byte offset for 128B bf16 rows / 256B fp32 rows
#define LDSW(row, b)  ((row)*128 + ((b) ^ (((row)&7)<<4)))
#define LDSWF(row, b) ((row)*256 + ((b) ^ (((row)&3)<<6)))

__global__ __launch_bounds__(256) void k_detect(const u32* __restrict__ idxw,
                                                int* __restrict__ flags) {
  __shared__ int cn;
  if (threadIdx.x == 0) cn = 0;
  __syncthreads();
  int c = 0;
  for (int k = 0; k < 16; ++k)
    c += (idxw[2*(threadIdx.x + k*256) + 1] != 0u) ? 1 : 0;
  atomicAdd(&cn, c);
  __syncthreads();
  if (threadIdx.x == 0) flags[0] = (cn == 0) ? 1 : 0;
}

__global__ __launch_bounds__(256) void k_hist(const u32* __restrict__ eidx,
                                              int* __restrict__ cntN,
                                              int* __restrict__ cntF,
                                              const int* __restrict__ flags) {
  const int e = blockIdx.x*256 + threadIdx.x;
  const int I64 = flags[0];
  const u32 src = I64 ? eidx[2*(size_t)e]        : eidx[e];
  const u32 dst = I64 ? eidx[2*((size_t)NE + e)] : eidx[(size_t)NE + e];
  atomicAdd(cntN + src, 1);
  atomicAdd(cntF + dst, 1);
}

__global__ __launch_bounds__(1024) void k_scan(const int* __restrict__ cnt,
                                               int* __restrict__ sta) {
  const int base = blockIdx.x * 50000;
  const int t = threadIdx.x;
  __shared__ int part[1024];
  int local[49];
  int s = 0;
  const int start = t * 49;
  #pragma unroll
  for (int j = 0; j < 49; ++j) {
    const int idx = start + j;
    const int v = (idx < 50000) ? cnt[base + idx] : 0;
    local[j] = s;
    s += v;
  }
  part[t] = s;
  __syncthreads();
  for (int off = 1; off < 1024; off <<= 1) {
    int v = 0;
    if (t >= off) v = part[t - off];
    __syncthreads();
    if (t >= off) part[t] += v;
    __syncthreads();
  }
  const int bv = (t > 0) ? part[t - 1] : 0;
  #pragma unroll
  for (int j = 0; j < 49; ++j) {
    const int idx = start + j;
    if (idx < 50000) sta[base + idx] = bv + local[j];
  }
}

__global__ __launch_bounds__(256) void k_fill(const u32* __restrict__ eidx,
                                              int* __restrict__ staN,
                                              int* __restrict__ staF,
                                              int* __restrict__ othN,
                                              int* __restrict__ othF,
                                              int* __restrict__ posN,
                                              int* __restrict__ posF,
                                              const int* __restrict__ flags) {
  const int e = blockIdx.x*256 + threadIdx.x;
  const int I64 = flags[0];
  const u32 src = I64 ? eidx[2*(size_t)e]        : eidx[e];
  const u32 dst = I64 ? eidx[2*((size_t)NE + e)] : eidx[(size_t)NE + e];
  const int pN = atomicAdd(staN + src, 1);
  const int pF = atomicAdd(staF + dst, 1);
  othN[pN] = (int)dst;
  othF[pF] = (int)src;
  posN[e] = pN;
  posF[e] = pF;
}

// pack 6 matrices (each 64x64 fp32, K x N) into MFMA B-fragments (bf16):
// matrix mi: frag f = kk*4+nt; Bpk[mi*4096+(f*64+lane)*8+j] = S[(kk*32+(lane>>4)*8+j)*64 + nt*16+(lane&15)]
__global__ __launch_bounds__(256) void k_bpack6(const float* __restrict__ P1,
                                                const float* __restrict__ W0,
                                                const float* __restrict__ Q0,
                                                const float* __restrict__ Q1,
                                                const float* __restrict__ W1,
                                                const float* __restrict__ W2,
                                                u16* __restrict__ Bpk) {
  const int v = blockIdx.x*256 + threadIdx.x;   // 0..24575
  const int mi = v >> 12;
  const int vv = v & 4095;
  const int f = vv >> 9, rem = vv & 511;
  const int lane = rem >> 3, j = rem & 7;
  const int kk = f >> 2, nt = f & 3;
  const int k = kk*32 + (lane>>4)*8 + j;
  const int col = nt*16 + (lane&15);
  const float* __restrict__ S = (mi==0) ? P1 : (mi==1) ? W0 : (mi==2) ? Q0
                              : (mi==3) ? Q1 : (mi==4) ? W1 : W2;
  Bpk[v] = f2bf(S[k*64 + col]);
}

// proj[row] (bf16) = emb[row] @ wt    (round-10 proven; 196-block, small)
__global__ __launch_bounds__(256) void k_proj(const float* __restrict__ emb,
                                              const float* __restrict__ wt,
                                              u16* __restrict__ outp) {
  const int row = blockIdx.x*256 + threadIdx.x;
  if (row >= 50000) return;
  float acc[DD];
  #pragma unroll
  for (int c = 0; c < DD; ++c) acc[c] = 0.f;
  #pragma unroll 4
  for (int k4 = 0; k4 < 16; ++k4) {
    const float4 v = *(const float4*)(emb + (size_t)row*DD + k4*4);
    const float f[4] = {v.x, v.y, v.z, v.w};
    const float* __restrict__ wr = wt + k4*4*DD;
    #pragma unroll
    for (int c = 0; c < DD; ++c) {
      float a = acc[c];
      #pragma unroll
      for (int j = 0; j < 4; ++j) a = fmaf(f[j], wr[j*DD + c], a);
      acc[c] = a;
    }
  }
  uint4 s[8]; u32* sw = (u32*)s;
  #pragma unroll
  for (int i = 0; i < 32; ++i) sw[i] = pk2(acc[2*i], acc[2*i+1]);
  uint4* o4 = (uint4*)(outp + (size_t)row*DD);
  #pragma unroll
  for (int i = 0; i < 8; ++i) o4[i] = s[i];
}

// MFMA ep (round-12 proven): X(64x64)@P1 + bP -> bf16 rows scattered to CSR slots
__global__ __launch_bounds__(256) void k_epm(const float* __restrict__ eemb,
                                             const u16* __restrict__ Bpk,
                                             const float* __restrict__ bP,
                                             const int* __restrict__ posN,
                                             const int* __restrict__ posF,
                                             u16* __restrict__ epN,
                                             u16* __restrict__ epF) {
  __shared__ u16 lds[4096];
  const int t = threadIdx.x;
  const int e0 = blockIdx.x * 64;
  #pragma unroll
  for (int i = 0; i < 4; ++i) {
    const int g = i*256 + t;
    const float4 v = ((const float4*)(eemb + (size_t)e0*DD))[g];
    const int row = g >> 4;
    const int b   = (g & 15) * 8;
    *(uint2*)((char*)lds + LDSW(row, b)) = make_uint2(pk2(v.x, v.y), pk2(v.z, v.w));
  }
  __syncthreads();
  const int w = t >> 6, l = t & 63;
  bf16x8 bf[8];
  #pragma unroll
  for (int f = 0; f < 8; ++f)
    bf[f] = *(const bf16x8*)(Bpk + (f*64 + l)*8);
  f32x4 acc[4];
  #pragma unroll
  for (int nt = 0; nt < 4; ++nt) {
    const float b = bP[nt*16 + (l&15)];
    acc[nt] = (f32x4){b, b, b, b};
  }
  const int arow = w*16 + (l&15);
  const bf16x8 a0 = *(const bf16x8*)((char*)lds + LDSW(arow, (l>>4)*16));
  const bf16x8 a1 = *(const bf16x8*)((char*)lds + LDSW(arow, 64 + (l>>4)*16));
  #pragma unroll
  for (int nt = 0; nt < 4; ++nt) {
    acc[nt] = __builtin_amdgcn_mfma_f32_16x16x32_bf16(a0, bf[nt],     acc[nt], 0, 0, 0);
    acc[nt] = __builtin_amdgcn_mfma_f32_16x16x32_bf16(a1, bf[4 + nt], acc[nt], 0, 0, 0);
  }
  #pragma unroll
  for (int nt = 0; nt < 4; ++nt) {
    #pragma unroll
    for (int r = 0; r < 4; ++r) {
      const int row = w*16 + (l>>4)*4 + r;
      const int col = nt*16 + (l&15);
      *(u16*)((char*)lds + LDSW(row, col*2)) = f2bf(acc[nt][r]);
    }
  }
  const int lr = l >> 2, seg = l & 3;
  const int row = w*16 + lr;
  const int e = e0 + row;
  const uint4 c0 = *(const uint4*)((char*)lds + LDSW(row, seg*32));
  const uint4 c1 = *(const uint4*)((char*)lds + LDSW(row, seg*32 + 16));
  const int pN = posN[e];
  *(uint4*)(epN + (size_t)pN*DD + seg*16)     = c0;
  *(uint4*)(epN + (size_t)pN*DD + seg*16 + 8) = c1;
  const int pF = posF[e];
  *(uint4*)(epF + (size_t)pF*DD + seg*16)     = c0;
  *(uint4*)(epF + (size_t)pF*DD + seg*16 + 8) = c1;
}

// MFMA update (replaces k_upd x2): per block 64 rows of one side.
// C1 = bQ + emb@Q0 + (msg/cnt)@Q1  -> fp32 out rows (coalesced via LDS)
// C2 = C1@Wseg                      -> bf16 rows over msg buffer (NOw/FOw)
__global__ __launch_bounds__(256) void k_updm(const float* __restrict__ node,
                                              const float* __restrict__ feat,
                                              const int* __restrict__ cntN,
                                              const int* __restrict__ cntF,
                                              float* msgN, float* msgF,
                                              const u16* __restrict__ Bpk,
                                              const float* __restrict__ bQ,
                                              float* __restrict__ outN,
                                              float* __restrict__ outF) {
  __shared__ char lb[40960];  // A1[0,8K) A2[8K,16K) C1h[16K,24K) C1f[24K,40K)
  const int t = threadIdx.x;
  const bool isN = blockIdx.x < UBLK;
  const int b = isN ? (int)blockIdx.x : (int)blockIdx.x - UBLK;
  const int r0 = b * 64;
  const float* __restrict__ emb = isN ? node : feat;
  const int* __restrict__ cnt = isN ? cntN : cntF;
  float* msgp = isN ? msgN : msgF;
  float* __restrict__ outp = isN ? outN : outF;
  const u16* __restrict__ BQ0 = Bpk + 2*4096;
  const u16* __restrict__ BQ1 = Bpk + 3*4096;
  const u16* __restrict__ BW  = Bpk + (isN ? 4 : 5)*4096;

  // stage A1 = emb tile, A2 = msg*inv tile (bf16, swizzled; zeros past tail)
  #pragma unroll
  for (int i = 0; i < 4; ++i) {
    const int g = i*256 + t;
    const int row = g >> 4;
    const int grow = r0 + row;
    const int q = g & 15;
    float4 v1 = make_float4(0.f, 0.f, 0.f, 0.f), v2 = v1;
    if (grow < 50000) {
      v1 = ((const float4*)(emb + (size_t)grow*DD))[q];
      const float inv = 1.f / fmaxf((float)cnt[grow], 1.f);
      const float4 mm = ((const float4*)(msgp + (size_t)grow*DD))[q];
      v2 = make_float4(mm.x*inv, mm.y*inv, mm.z*inv, mm.w*inv);
    }
    *(uint2*)(lb + LDSW(row, q*8))        = make_uint2(pk2(v1.x,v1.y), pk2(v1.z,v1.w));
    *(uint2*)(lb + 8192 + LDSW(row, q*8)) = make_uint2(pk2(v2.x,v2.y), pk2(v2.z,v2.w));
  }
  __syncthreads();
  // all LDS traffic below is wave-local (rows w*16..w*16+15)
  const int w = t >> 6, l = t & 63;
  bf16x8 q0f[8], q1f[8];
  #pragma unroll
  for (int f = 0; f < 8; ++f) {
    q0f[f] = *(const bf16x8*)(BQ0 + (f*64 + l)*8);
    q1f[f] = *(const bf16x8*)(BQ1 + (f*64 + l)*8);
  }
  f32x4 acc[4];
  #pragma unroll
  for (int nt = 0; nt < 4; ++nt) {
    const float bb = bQ[nt*16 + (l&15)];
    acc[nt] = (f32x4){bb, bb, bb, bb};
  }
  const int arow = w*16 + (l&15);
  const bf16x8 e0 = *(const bf16x8*)(lb + LDSW(arow, (l>>4)*16));
  const bf16x8 e1 = *(const bf16x8*)(lb + LDSW(arow, 64 + (l>>4)*16));
  const bf16x8 m0 = *(const bf16x8*)(lb + 8192 + LDSW(arow, (l>>4)*16));
  const bf16x8 m1 = *(const bf16x8*)(lb + 8192 + LDSW(arow, 64 + (l>>4)*16));
  #pragma unroll
  for (int nt = 0; nt < 4; ++nt) {
    acc[nt] = __builtin_amdgcn_mfma_f32_16x16x32_bf16(e0, q0f[nt],   acc[nt], 0, 0, 0);
    acc[nt] = __builtin_amdgcn_mfma_f32_16x16x32_bf16(e1, q0f[4+nt], acc[nt], 0, 0, 0);
    acc[nt] = __builtin_amdgcn_mfma_f32_16x16x32_bf16(m0, q1f[nt],   acc[nt], 0, 0, 0);
    acc[nt] = __builtin_amdgcn_mfma_f32_16x16x32_bf16(m1, q1f[4+nt], acc[nt], 0, 0, 0);
  }
  // C1 -> LDS: fp32 (for out store) + bf16 (A of second matmul)
  #pragma unroll
  for (int nt = 0; nt < 4; ++nt) {
    #pragma unroll
    for (int r = 0; r < 4; ++r) {
      const int row = w*16 + (l>>4)*4 + r;
      const int col = nt*16 + (l&15);
      const float val = acc[nt][r];
      *(float*)(lb + 24576 + LDSWF(row, col*4)) = val;
      *(u16*)(lb + 16384 + LDSW(row, col*2)) = f2bf(val);
    }
  }
  // coalesced fp32 out store (1KB per wave-instruction)
  #pragma unroll
  for (int i = 0; i < 4; ++i) {
    const int row = w*16 + i*4 + (l>>4);
    const int grow = r0 + row;
    if (grow < 50000) {
      const uint4 vv = *(const uint4*)(lb + 24576 + LDSWF(row, (l&15)*16));
      *(uint4*)((u32*)(outp + (size_t)grow*DD) + (l&15)*4) = vv;
    }
  }
  // second matmul: C2 = C1 @ Wseg
  bf16x8 wf[8];
  #pragma unroll
  for (int f = 0; f < 8; ++f)
    wf[f] = *(const bf16x8*)(BW + (f*64 + l)*8);
  f32x4 acc2[4];
  #pragma unroll
  for (int nt = 0; nt < 4; ++nt) acc2[nt] = (f32x4){0.f, 0.f, 0.f, 0.f};
  const bf16x8 c0 = *(const bf16x8*)(lb + 16384 + LDSW(arow, (l>>4)*16));
  const bf16x8 c1 = *(const bf16x8*)(lb + 16384 + LDSW(arow, 64 + (l>>4)*16));
  #pragma unroll
  for (int nt = 0; nt < 4; ++nt) {
    acc2[nt] = __builtin_amdgcn_mfma_f32_16x16x32_bf16(c0, wf[nt],   acc2[nt], 0, 0, 0);
    acc2[nt] = __builtin_amdgcn_mfma_f32_16x16x32_bf16(c1, wf[4+nt], acc2[nt], 0, 0, 0);
  }
  // C2 -> bf16 LDS (reuse A1 region; wave-local, in-order after e0/e1 reads)
  #pragma unroll
  for (int nt = 0; nt < 4; ++nt) {
    #pragma unroll
    for (int r = 0; r < 4; ++r) {
      const int row = w*16 + (l>>4)*4 + r;
      const int col = nt*16 + (l&15);
      *(u16*)(lb + LDSW(row, col*2)) = f2bf(acc2[nt][r]);
    }
  }
  #pragma unroll
  for (int i = 0; i < 2; ++i) {
    const int row = w*16 + i*8 + (l>>3);
    const int grow = r0 + row;
    if (grow < 50000) {
      const uint4 vv = *(const uint4*)(lb + LDSW(row, (l&7)*16));
      *(uint4*)((u16*)(msgp + (size_t)grow*DD) + (l&7)*8) = vv;
    }
  }
}

// MFMA edge_out (round-13 proven)
__global__ __launch_bounds__(256) void k_eoutm(const float* __restrict__ eemb,
                                               const u32* __restrict__ eidx,
                                               const u16* __restrict__ BpkW,
                                               const float* __restrict__ bW,
                                               const u16* __restrict__ NOw,
                                               const u16* __restrict__ FOw,
                                               float* __restrict__ outp,
                                               const int* __restrict__ flags) {
  __shared__ u16 lds[4096];
  const int t = threadIdx.x;
  const int e0 = blockIdx.x * 64;
  #pragma unroll
  for (int i = 0; i < 4; ++i) {
    const int g = i*256 + t;
    const float4 v = ((const float4*)(eemb + (size_t)e0*DD))[g];
    const int row = g >> 4;
    const int b   = (g & 15) * 8;
    *(uint2*)((char*)lds + LDSW(row, b)) = make_uint2(pk2(v.x, v.y), pk2(v.z, v.w));
  }
  __syncthreads();
  const int w = t >> 6, l = t & 63;
  bf16x8 bf[8];
  #pragma unroll
  for (int f = 0; f < 8; ++f)
    bf[f] = *(const bf16x8*)(BpkW + (f*64 + l)*8);
  f32x4 acc[4];
  #pragma unroll
  for (int nt = 0; nt < 4; ++nt) {
    const float b = bW[nt*16 + (l&15)];
    acc[nt] = (f32x4){b, b, b, b};
  }
  const int arow = w*16 + (l&15);
  const bf16x8 a0 = *(const bf16x8*)((char*)lds + LDSW(arow, (l>>4)*16));
  const bf16x8 a1 = *(const bf16x8*)((char*)lds + LDSW(arow, 64 + (l>>4)*16));
  #pragma unroll
  for (int nt = 0; nt < 4; ++nt) {
    acc[nt] = __builtin_amdgcn_mfma_f32_16x16x32_bf16(a0, bf[nt],     acc[nt], 0, 0, 0);
    acc[nt] = __builtin_amdgcn_mfma_f32_16x16x32_bf16(a1, bf[4 + nt], acc[nt], 0, 0, 0);
  }
  #pragma unroll
  for (int nt = 0; nt < 4; ++nt) {
    #pragma unroll
    for (int r = 0; r < 4; ++r) {
      const int row = w*16 + (l>>4)*4 + r;
      const int col = nt*16 + (l&15);
      *(u16*)((char*)lds + LDSW(row, col*2)) = f2bf(acc[nt][r]);
    }
  }
  const int lr = l >> 2, seg = l & 3;
  const int row = w*16 + lr;
  const int e = e0 + row;
  const int I64 = flags[0];
  const u32 src = I64 ? eidx[2*(size_t)e]        : eidx[e];
  const u32 dst = I64 ? eidx[2*((size_t)NE + e)] : eidx[(size_t)NE + e];
  const uint4 c0 = *(const uint4*)((char*)lds + LDSW(row, seg*32));
  const uint4 c1 = *(const uint4*)((char*)lds + LDSW(row, seg*32 + 16));
  float r[16];
  {
    const uint4 v = c0;
    r[0]=bf2f((u16)(v.x&0xffffu)); r[1]=bf2f((u16)(v.x>>16));
    r[2]=bf2f((u16)(v.y&0xffffu)); r[3]=bf2f((u16)(v.y>>16));
    r[4]=bf2f((u16)(v.z&0xffffu)); r[5]=bf2f((u16)(v.z>>16));
    r[6]=bf2f((u16)(v.w&0xffffu)); r[7]=bf2f((u16)(v.w>>16));
  }
  {
    const uint4 v = c1;
    r[8]=bf2f((u16)(v.x&0xffffu));  r[9]=bf2f((u16)(v.x>>16));
    r[10]=bf2f((u16)(v.y&0xffffu)); r[11]=bf2f((u16)(v.y>>16));
    r[12]=bf2f((u16)(v.z&0xffffu)); r[13]=bf2f((u16)(v.z>>16));
    r[14]=bf2f((u16)(v.w&0xffffu)); r[15]=bf2f((u16)(v.w>>16));
  }
  #pragma unroll
  for (int half = 0; half < 2; ++half) {
    const uint4 vn = *(const uint4*)(NOw + (size_t)src*128 + seg*16 + half*8);
    const uint4 vf = *(const uint4*)(FOw + (size_t)dst*128 + seg*16 + half*8);
    float* rr = r + half*8;
    rr[0]+=bf2f((u16)(vn.x&0xffffu))+bf2f((u16)(vf.x&0xffffu));
    rr[1]+=bf2f((u16)(vn.x>>16))+bf2f((u16)(vf.x>>16));
    rr[2]+=bf2f((u16)(vn.y&0xffffu))+bf2f((u16)(vf.y&0xffffu));
    rr[3]+=bf2f((u16)(vn.y>>16))+bf2f((u16)(vf.y>>16));
    rr[4]+=bf2f((u16)(vn.z&0xffffu))+bf2f((u16)(vf.z&0xffffu));
    rr[5]+=bf2f((u16)(vn.z>>16))+bf2f((u16)(vf.z>>16));
    rr[6]+=bf2f((u16)(vn.w&0xffffu))+bf2f((u16)(vf.w&0xffffu));
    rr[7]+=bf2f((u16)(vn.w>>16))+bf2f((u16)(vf.w>>16));
  }
  float4* o4 = (float4*)(outp + (size_t)e*DD + seg*16);
  #pragma unroll
  for (int i = 0; i < 4; ++i)
    o4[i] = make_float4(r[4*i], r[4*i+1], r[4*i+2], r[4*i+3]);
}

// one wave per node: msg[n] = SUM over CSR range of relu(eps[i] + proj[oth[i]])
__global__ __launch_bounds__(256) void k_gather2(const int* __restrict__ sta,
                                                 const int* __restrict__ cnt,
                                                 const int* __restrict__ oth,
                                                 const u16* __restrict__ eps,
                                                 const u16* __restrict__ proj,
                                                 float* __restrict__ msg) {
  const int n = blockIdx.x*4 + (threadIdx.x >> 6);
  const int lane = threadIdx.x & 63;
  const int end = sta[n];
  const int c = cnt[n];
  float acc = 0.f;
  #pragma unroll 4
  for (int i = end - c; i < end; ++i) {
    const int o = oth[i];
    acc += fmaxf(bf2f(eps[(size_t)i*DD + lane]) + bf2f(proj[(size_t)o*DD + lane]), 0.f);
  }
  msg[(size_t)n*DD + lane] = acc;
}

extern "C" void kernel_launch(void* const* d_in, const int* in_sizes, int n_in,
                              void* d_out, int out_size, void* d_ws, size_t ws_size,
                              hipStream_t stream) {
  if (ws_size < (size_t)WS_FLOATS * 4) return;
  const float* node = (const float*)d_in[0];
  const float* eemb = (const float*)d_in[1];
  const float* feat = (const float*)d_in[2];
  const u32*   eidx = (const u32*)d_in[3];
  const float* P  = (const float*)d_in[4];
  const float* bP = (const float*)d_in[5];
  const float* Q  = (const float*)d_in[6];
  const float* bQ = (const float*)d_in[7];
  const float* W  = (const float*)d_in[8];
  const float* bW = (const float*)d_in[9];
  float* wsf = (float*)d_ws;
  int*   wsi = (int*)d_ws;
  float* out = (float*)d_out;

  u16* Fp_h = (u16*)out;
  u16* epN_h = (u16*)(out + (size_t)ND*DD);
  u16* epF_h = epN_h + (size_t)NE*DD;
  u16* Np_h = (u16*)(out + (size_t)(ND + NE)*DD);
  float* msgN = wsf + OFF_MSGN;
  float* msgF = wsf + OFF_MSGF;
  int* posN = (int*)(wsf + OFF_MSGN);   // overlays msgN start; dead after k_epm
  int* posF = posN + NE;
  u16* Bpk = (u16*)(wsf + OFF_BPK);     // [P1|W0|Q0|Q1|W1|W2] x 4096

  hipMemsetAsync((void*)(wsi + OFF_CNTN), 0, (size_t)100000 * 4, stream);
  k_detect<<<1, 256, 0, stream>>>(eidx, wsi + OFF_FLAGS);
  k_bpack6<<<96, 256, 0, stream>>>(P + 64*DD, W, Q, Q + 64*DD, W + 64*DD, W + 128*DD, Bpk);
  k_hist<<<EBLK, 256, 0, stream>>>(eidx, wsi + OFF_CNTN, wsi + OFF_CNTF, wsi + OFF_FLAGS);
  k_scan<<<2, 1024, 0, stream>>>(wsi + OFF_CNTN, wsi + OFF_STAN);
  k_fill<<<EBLK, 256, 0, stream>>>(eidx, wsi + OFF_STAN, wsi + OFF_STAF,
                                   wsi + OFF_OTHN, wsi + OFF_OTHF,
                                   posN, posF, wsi + OFF_FLAGS);
  k_proj<<<NBLK, 256, 0, stream>>>(feat, P, Fp_h);
  k_proj<<<NBLK, 256, 0, stream>>>(node, P, Np_h);
  k_epm<<<12500, 256, 0, stream>>>(eemb, Bpk, bP, posN, posF, epN_h, epF_h);
  k_gather2<<<12500, 256, 0, stream>>>(wsi + OFF_STAN, wsi + OFF_CNTN,
                                       wsi + OFF_OTHN, epN_h, Fp_h, msgN);
  k_gather2<<<12500, 256, 0, stream>>>(wsi + OFF_STAF, wsi + OFF_CNTF,
                                       wsi + OFF_OTHF, epF_h, Np_h, msgF);
  k_updm<<<2*UBLK, 256, 0, stream>>>(node, feat, wsi + OFF_CNTN, wsi + OFF_CNTF,
                                     msgN, msgF, Bpk, bQ,
                                     out, out + (size_t)(ND + NE)*DD);
  k_eoutm<<<12500, 256, 0, stream>>>(eemb, eidx, Bpk + 4096, bW,
                                     (const u16*)msgN, (const u16*)msgF,
                                     out + (size_t)ND*DD, wsi + OFF_FLAGS);
}

// Round 15
// 541.938 us; speedup vs baseline: 2.7403x; 1.1965x over previous
//
#include <hip/hip_runtime.h>

typedef unsigned int u32;
typedef unsigned short u16;
using bf16x8 = __attribute__((ext_vector_type(8))) short;
using f32x4  = __attribute__((ext_vector_type(4))) float;

#define ND 50000
#define NF 50000
#define NE 800000
#define DD 64
#define NBLK 196   // ceil(50000/256)
#define EBLK 3125  // 800000/256
#define UBLK 782   // ceil(50000/64)

// ---- ws float-index layout ----
#define OFF_FLAGS 0                        // [0] = idx-is-int64
#define OFF_CNTN  64
#define OFF_CNTF  (OFF_CNTN + 50000)
#define OFF_STAN  (OFF_CNTF + 50000)       // start offsets (never mutated after scan)
#define OFF_STAF  (OFF_STAN + 50000)
#define OFF_OTHN  (OFF_STAF + 50000)
#define OFF_OTHF  (OFF_OTHN + 800000)
#define OFF_MSGN  (OFF_OTHF + 800000)      // first 1.6M floats: rankN/rankF (dead after k_epm)
#define OFF_MSGF  (OFF_MSGN + 3200000)
#define OFF_BPK   (OFF_MSGF + 3200000)     // 12288 floats: 6*4096 bf16 B-frags
                                           // [P1 | W0 | Q0 | Q1 | W1 | W2]
#define WS_FLOATS (OFF_BPK + 12288)

__device__ __forceinline__ u16 f2bf(float x){ union{u32 u;float f;}v; v.f=x; u32 r=v.u+0x7fffu+((v.u>>16)&1u); return (u16)(r>>16); }
__device__ __forceinline__ float bf2f(u16 h){ union{u32 u;float f;}v; v.u=((u32)h)<<16; return v.f; }
__device__ __forceinline__ u32 pk2(float a,float b){ return (u32)f2bf(a) | ((u32)f2bf(b)<<16); }

// swizzled LDS byte offset for 128B bf16 rows / 256B fp32 rows
#define LDSW(row, b)  ((row)*128 + ((b) ^ (((row)&7)<<4)))
#define LDSWF(row, b) ((row)*256 + ((b) ^ (((row)&3)<<6)))

__global__ __launch_bounds__(256) void k_detect(const u32* __restrict__ idxw,
                                                int* __restrict__ flags) {
  __shared__ int cn;
  if (threadIdx.x == 0) cn = 0;
  __syncthreads();
  int c = 0;
  for (int k = 0; k < 16; ++k)
    c += (idxw[2*(threadIdx.x + k*256) + 1] != 0u) ? 1 : 0;
  atomicAdd(&cn, c);
  __syncthreads();
  if (threadIdx.x == 0) flags[0] = (cn == 0) ? 1 : 0;
}

// histogram + per-edge rank capture (replaces hist AND fill's atomics)
__global__ __launch_bounds__(256) void k_hist2(const u32* __restrict__ eidx,
                                               int* __restrict__ cntN,
                                               int* __restrict__ cntF,
                                               int* __restrict__ rankN,
                                               int* __restrict__ rankF,
                                               const int* __restrict__ flags) {
  const int e = blockIdx.x*256 + threadIdx.x;
  const int I64 = flags[0];
  const u32 src = I64 ? eidx[2*(size_t)e]        : eidx[e];
  const u32 dst = I64 ? eidx[2*((size_t)NE + e)] : eidx[(size_t)NE + e];
  rankN[e] = atomicAdd(cntN + src, 1);
  rankF[e] = atomicAdd(cntF + dst, 1);
}

__global__ __launch_bounds__(1024) void k_scan(const int* __restrict__ cnt,
                                               int* __restrict__ sta) {
  const int base = blockIdx.x * 50000;
  const int t = threadIdx.x;
  __shared__ int part[1024];
  int local[49];
  int s = 0;
  const int start = t * 49;
  #pragma unroll
  for (int j = 0; j < 49; ++j) {
    const int idx = start + j;
    const int v = (idx < 50000) ? cnt[base + idx] : 0;
    local[j] = s;
    s += v;
  }
  part[t] = s;
  __syncthreads();
  for (int off = 1; off < 1024; off <<= 1) {
    int v = 0;
    if (t >= off) v = part[t - off];
    __syncthreads();
    if (t >= off) part[t] += v;
    __syncthreads();
  }
  const int bv = (t > 0) ? part[t - 1] : 0;
  #pragma unroll
  for (int j = 0; j < 49; ++j) {
    const int idx = start + j;
    if (idx < 50000) sta[base + idx] = bv + local[j];
  }
}

// pack 6 matrices (each 64x64 fp32, K x N) into MFMA B-fragments (bf16)
__global__ __launch_bounds__(256) void k_bpack6(const float* __restrict__ P1,
                                                const float* __restrict__ W0,
                                                const float* __restrict__ Q0,
                                                const float* __restrict__ Q1,
                                                const float* __restrict__ W1,
                                                const float* __restrict__ W2,
                                                u16* __restrict__ Bpk) {
  const int v = blockIdx.x*256 + threadIdx.x;   // 0..24575
  const int mi = v >> 12;
  const int vv = v & 4095;
  const int f = vv >> 9, rem = vv & 511;
  const int lane = rem >> 3, j = rem & 7;
  const int kk = f >> 2, nt = f & 3;
  const int k = kk*32 + (lane>>4)*8 + j;
  const int col = nt*16 + (lane&15);
  const float* __restrict__ S = (mi==0) ? P1 : (mi==1) ? W0 : (mi==2) ? Q0
                              : (mi==3) ? Q1 : (mi==4) ? W1 : W2;
  Bpk[v] = f2bf(S[k*64 + col]);
}

// proj[row] (bf16) = emb[row] @ wt    (round-10 proven)
__global__ __launch_bounds__(256) void k_proj(const float* __restrict__ emb,
                                              const float* __restrict__ wt,
                                              u16* __restrict__ outp) {
  const int row = blockIdx.x*256 + threadIdx.x;
  if (row >= 50000) return;
  float acc[DD];
  #pragma unroll
  for (int c = 0; c < DD; ++c) acc[c] = 0.f;
  #pragma unroll 4
  for (int k4 = 0; k4 < 16; ++k4) {
    const float4 v = *(const float4*)(emb + (size_t)row*DD + k4*4);
    const float f[4] = {v.x, v.y, v.z, v.w};
    const float* __restrict__ wr = wt + k4*4*DD;
    #pragma unroll
    for (int c = 0; c < DD; ++c) {
      float a = acc[c];
      #pragma unroll
      for (int j = 0; j < 4; ++j) a = fmaf(f[j], wr[j*DD + c], a);
      acc[c] = a;
    }
  }
  uint4 s[8]; u32* sw = (u32*)s;
  #pragma unroll
  for (int i = 0; i < 32; ++i) sw[i] = pk2(acc[2*i], acc[2*i+1]);
  uint4* o4 = (uint4*)(outp + (size_t)row*DD);
  #pragma unroll
  for (int i = 0; i < 8; ++i) o4[i] = s[i];
}

// MFMA ep: X(64x64)@P1 + bP -> bf16 rows scattered to CSR slots.
// pos computed inline (sta[node] + rank[e]); oth written here (one lane per edge).
__global__ __launch_bounds__(256) void k_epm(const float* __restrict__ eemb,
                                             const u32* __restrict__ eidx,
                                             const u16* __restrict__ Bpk,
                                             const float* __restrict__ bP,
                                             const int* __restrict__ staN,
                                             const int* __restrict__ staF,
                                             const int* __restrict__ rankN,
                                             const int* __restrict__ rankF,
                                             int* __restrict__ othN,
                                             int* __restrict__ othF,
                                             u16* __restrict__ epN,
                                             u16* __restrict__ epF,
                                             const int* __restrict__ flags) {
  __shared__ u16 lds[4096];
  const int t = threadIdx.x;
  const int e0 = blockIdx.x * 64;
  #pragma unroll
  for (int i = 0; i < 4; ++i) {
    const int g = i*256 + t;
    const float4 v = ((const float4*)(eemb + (size_t)e0*DD))[g];
    const int row = g >> 4;
    const int b   = (g & 15) * 8;
    *(uint2*)((char*)lds + LDSW(row, b)) = make_uint2(pk2(v.x, v.y), pk2(v.z, v.w));
  }
  __syncthreads();
  const int w = t >> 6, l = t & 63;
  bf16x8 bf[8];
  #pragma unroll
  for (int f = 0; f < 8; ++f)
    bf[f] = *(const bf16x8*)(Bpk + (f*64 + l)*8);
  f32x4 acc[4];
  #pragma unroll
  for (int nt = 0; nt < 4; ++nt) {
    const float b = bP[nt*16 + (l&15)];
    acc[nt] = (f32x4){b, b, b, b};
  }
  const int arow = w*16 + (l&15);
  const bf16x8 a0 = *(const bf16x8*)((char*)lds + LDSW(arow, (l>>4)*16));
  const bf16x8 a1 = *(const bf16x8*)((char*)lds + LDSW(arow, 64 + (l>>4)*16));
  #pragma unroll
  for (int nt = 0; nt < 4; ++nt) {
    acc[nt] = __builtin_amdgcn_mfma_f32_16x16x32_bf16(a0, bf[nt],     acc[nt], 0, 0, 0);
    acc[nt] = __builtin_amdgcn_mfma_f32_16x16x32_bf16(a1, bf[4 + nt], acc[nt], 0, 0, 0);
  }
  #pragma unroll
  for (int nt = 0; nt < 4; ++nt) {
    #pragma unroll
    for (int r = 0; r < 4; ++r) {
      const int row = w*16 + (l>>4)*4 + r;
      const int col = nt*16 + (l&15);
      *(u16*)((char*)lds + LDSW(row, col*2)) = f2bf(acc[nt][r]);
    }
  }
  const int lr = l >> 2, seg = l & 3;
  const int row = w*16 + lr;
  const int e = e0 + row;
  const int I64 = flags[0];
  const u32 src = I64 ? eidx[2*(size_t)e]        : eidx[e];
  const u32 dst = I64 ? eidx[2*((size_t)NE + e)] : eidx[(size_t)NE + e];
  const int pN = staN[src] + rankN[e];
  const int pF = staF[dst] + rankF[e];
  if (seg == 0) { othN[pN] = (int)dst; othF[pF] = (int)src; }
  const uint4 c0 = *(const uint4*)((char*)lds + LDSW(row, seg*32));
  const uint4 c1 = *(const uint4*)((char*)lds + LDSW(row, seg*32 + 16));
  *(uint4*)(epN + (size_t)pN*DD + seg*16)     = c0;
  *(uint4*)(epN + (size_t)pN*DD + seg*16 + 8) = c1;
  *(uint4*)(epF + (size_t)pF*DD + seg*16)     = c0;
  *(uint4*)(epF + (size_t)pF*DD + seg*16 + 8) = c1;
}

// MFMA update (round-14 proven)
__global__ __launch_bounds__(256) void k_updm(const float* __restrict__ node,
                                              const float* __restrict__ feat,
                                              const int* __restrict__ cntN,
                                              const int* __restrict__ cntF,
                                              float* msgN, float* msgF,
                                              const u16* __restrict__ Bpk,
                                              const float* __restrict__ bQ,
                                              float* __restrict__ outN,
                                              float* __restrict__ outF) {
  __shared__ char lb[40960];  // A1[0,8K) A2[8K,16K) C1h[16K,24K) C1f[24K,40K)
  const int t = threadIdx.x;
  const bool isN = blockIdx.x < UBLK;
  const int b = isN ? (int)blockIdx.x : (int)blockIdx.x - UBLK;
  const int r0 = b * 64;
  const float* __restrict__ emb = isN ? node : feat;
  const int* __restrict__ cnt = isN ? cntN : cntF;
  float* msgp = isN ? msgN : msgF;
  float* __restrict__ outp = isN ? outN : outF;
  const u16* __restrict__ BQ0 = Bpk + 2*4096;
  const u16* __restrict__ BQ1 = Bpk + 3*4096;
  const u16* __restrict__ BW  = Bpk + (isN ? 4 : 5)*4096;

  #pragma unroll
  for (int i = 0; i < 4; ++i) {
    const int g = i*256 + t;
    const int row = g >> 4;
    const int grow = r0 + row;
    const int q = g & 15;
    float4 v1 = make_float4(0.f, 0.f, 0.f, 0.f), v2 = v1;
    if (grow < 50000) {
      v1 = ((const float4*)(emb + (size_t)grow*DD))[q];
      const float inv = 1.f / fmaxf((float)cnt[grow], 1.f);
      const float4 mm = ((const float4*)(msgp + (size_t)grow*DD))[q];
      v2 = make_float4(mm.x*inv, mm.y*inv, mm.z*inv, mm.w*inv);
    }
    *(uint2*)(lb + LDSW(row, q*8))        = make_uint2(pk2(v1.x,v1.y), pk2(v1.z,v1.w));
    *(uint2*)(lb + 8192 + LDSW(row, q*8)) = make_uint2(pk2(v2.x,v2.y), pk2(v2.z,v2.w));
  }
  __syncthreads();
  const int w = t >> 6, l = t & 63;
  bf16x8 q0f[8], q1f[8];
  #pragma unroll
  for (int f = 0; f < 8; ++f) {
    q0f[f] = *(const bf16x8*)(BQ0 + (f*64 + l)*8);
    q1f[f] = *(const bf16x8*)(BQ1 + (f*64 + l)*8);
  }
  f32x4 acc[4];
  #pragma unroll
  for (int nt = 0; nt < 4; ++nt) {
    const float bb = bQ[nt*16 + (l&15)];
    acc[nt] = (f32x4){bb, bb, bb, bb};
  }
  const int arow = w*16 + (l&15);
  const bf16x8 e0 = *(const bf16x8*)(lb + LDSW(arow, (l>>4)*16));
  const bf16x8 e1 = *(const bf16x8*)(lb + LDSW(arow, 64 + (l>>4)*16));
  const bf16x8 m0 = *(const bf16x8*)(lb + 8192 + LDSW(arow, (l>>4)*16));
  const bf16x8 m1 = *(const bf16x8*)(lb + 8192 + LDSW(arow, 64 + (l>>4)*16));
  #pragma unroll
  for (int nt = 0; nt < 4; ++nt) {
    acc[nt] = __builtin_amdgcn_mfma_f32_16x16x32_bf16(e0, q0f[nt],   acc[nt], 0, 0, 0);
    acc[nt] = __builtin_amdgcn_mfma_f32_16x16x32_bf16(e1, q0f[4+nt], acc[nt], 0, 0, 0);
    acc[nt] = __builtin_amdgcn_mfma_f32_16x16x32_bf16(m0, q1f[nt],   acc[nt], 0, 0, 0);
    acc[nt] = __builtin_amdgcn_mfma_f32_16x16x32_bf16(m1, q1f[4+nt], acc[nt], 0, 0, 0);
  }
  #pragma unroll
  for (int nt = 0; nt < 4; ++nt) {
    #pragma unroll
    for (int r = 0; r < 4; ++r) {
      const int row = w*16 + (l>>4)*4 + r;
      const int col = nt*16 + (l&15);
      const float val = acc[nt][r];
      *(float*)(lb + 24576 + LDSWF(row, col*4)) = val;
      *(u16*)(lb + 16384 + LDSW(row, col*2)) = f2bf(val);
    }
  }
  #pragma unroll
  for (int i = 0; i < 4; ++i) {
    const int row = w*16 + i*4 + (l>>4);
    const int grow = r0 + row;
    if (grow < 50000) {
      const uint4 vv = *(const uint4*)(lb + 24576 + LDSWF(row, (l&15)*16));
      *(uint4*)((u32*)(outp + (size_t)grow*DD) + (l&15)*4) = vv;
    }
  }
  bf16x8 wf[8];
  #pragma unroll
  for (int f = 0; f < 8; ++f)
    wf[f] = *(const bf16x8*)(BW + (f*64 + l)*8);
  f32x4 acc2[4];
  #pragma unroll
  for (int nt = 0; nt < 4; ++nt) acc2[nt] = (f32x4){0.f, 0.f, 0.f, 0.f};
  const bf16x8 c0 = *(const bf16x8*)(lb + 16384 + LDSW(arow, (l>>4)*16));
  const bf16x8 c1 = *(const bf16x8*)(lb + 16384 + LDSW(arow, 64 + (l>>4)*16));
  #pragma unroll
  for (int nt = 0; nt < 4; ++nt) {
    acc2[nt] = __builtin_amdgcn_mfma_f32_16x16x32_bf16(c0, wf[nt],   acc2[nt], 0, 0, 0);
    acc2[nt] = __builtin_amdgcn_mfma_f32_16x16x32_bf16(c1, wf[4+nt], acc2[nt], 0, 0, 0);
  }
  #pragma unroll
  for (int nt = 0; nt < 4; ++nt) {
    #pragma unroll
    for (int r = 0; r < 4; ++r) {
      const int row = w*16 + (l>>4)*4 + r;
      const int col = nt*16 + (l&15);
      *(u16*)(lb + LDSW(row, col*2)) = f2bf(acc2[nt][r]);
    }
  }
  #pragma unroll
  for (int i = 0; i < 2; ++i) {
    const int row = w*16 + i*8 + (l>>3);
    const int grow = r0 + row;
    if (grow < 50000) {
      const uint4 vv = *(const uint4*)(lb + LDSW(row, (l&7)*16));
      *(uint4*)((u16*)(msgp + (size_t)grow*DD) + (l&7)*8) = vv;
    }
  }
}

// MFMA edge_out (round-13 proven)
__global__ __launch_bounds__(256) void k_eoutm(const float* __restrict__ eemb,
                                               const u32* __restrict__ eidx,
                                               const u16* __restrict__ BpkW,
                                               const float* __restrict__ bW,
                                               const u16* __restrict__ NOw,
                                               const u16* __restrict__ FOw,
                                               float* __restrict__ outp,
                                               const int* __restrict__ flags) {
  __shared__ u16 lds[4096];
  const int t = threadIdx.x;
  const int e0 = blockIdx.x * 64;
  #pragma unroll
  for (int i = 0; i < 4; ++i) {
    const int g = i*256 + t;
    const float4 v = ((const float4*)(eemb + (size_t)e0*DD))[g];
    const int row = g >> 4;
    const int b   = (g & 15) * 8;
    *(uint2*)((char*)lds + LDSW(row, b)) = make_uint2(pk2(v.x, v.y), pk2(v.z, v.w));
  }
  __syncthreads();
  const int w = t >> 6, l = t & 63;
  bf16x8 bf[8];
  #pragma unroll
  for (int f = 0; f < 8; ++f)
    bf[f] = *(const bf16x8*)(BpkW + (f*64 + l)*8);
  f32x4 acc[4];
  #pragma unroll
  for (int nt = 0; nt < 4; ++nt) {
    const float b = bW[nt*16 + (l&15)];
    acc[nt] = (f32x4){b, b, b, b};
  }
  const int arow = w*16 + (l&15);
  const bf16x8 a0 = *(const bf16x8*)((char*)lds + LDSW(arow, (l>>4)*16));
  const bf16x8 a1 = *(const bf16x8*)((char*)lds + LDSW(arow, 64 + (l>>4)*16));
  #pragma unroll
  for (int nt = 0; nt < 4; ++nt) {
    acc[nt] = __builtin_amdgcn_mfma_f32_16x16x32_bf16(a0, bf[nt],     acc[nt], 0, 0, 0);
    acc[nt] = __builtin_amdgcn_mfma_f32_16x16x32_bf16(a1, bf[4 + nt], acc[nt], 0, 0, 0);
  }
  #pragma unroll
  for (int nt = 0; nt < 4; ++nt) {
    #pragma unroll
    for (int r = 0; r < 4; ++r) {
      const int row = w*16 + (l>>4)*4 + r;
      const int col = nt*16 + (l&15);
      *(u16*)((char*)lds + LDSW(row, col*2)) = f2bf(acc[nt][r]);
    }
  }
  const int lr = l >> 2, seg = l & 3;
  const int row = w*16 + lr;
  const int e = e0 + row;
  const int I64 = flags[0];
  const u32 src = I64 ? eidx[2*(size_t)e]        : eidx[e];
  const u32 dst = I64 ? eidx[2*((size_t)NE + e)] : eidx[(size_t)NE + e];
  const uint4 c0 = *(const uint4*)((char*)lds + LDSW(row, seg*32));
  const uint4 c1 = *(const uint4*)((char*)lds + LDSW(row, seg*32 + 16));
  float r[16];
  {
    const uint4 v = c0;
    r[0]=bf2f((u16)(v.x&0xffffu)); r[1]=bf2f((u16)(v.x>>16));
    r[2]=bf2f((u16)(v.y&0xffffu)); r[3]=bf2f((u16)(v.y>>16));
    r[4]=bf2f((u16)(v.z&0xffffu)); r[5]=bf2f((u16)(v.z>>16));
    r[6]=bf2f((u16)(v.w&0xffffu)); r[7]=bf2f((u16)(v.w>>16));
  }
  {
    const uint4 v = c1;
    r[8]=bf2f((u16)(v.x&0xffffu));  r[9]=bf2f((u16)(v.x>>16));
    r[10]=bf2f((u16)(v.y&0xffffu)); r[11]=bf2f((u16)(v.y>>16));
    r[12]=bf2f((u16)(v.z&0xffffu)); r[13]=bf2f((u16)(v.z>>16));
    r[14]=bf2f((u16)(v.w&0xffffu)); r[15]=bf2f((u16)(v.w>>16));
  }
  #pragma unroll
  for (int half = 0; half < 2; ++half) {
    const uint4 vn = *(const uint4*)(NOw + (size_t)src*128 + seg*16 + half*8);
    const uint4 vf = *(const uint4*)(FOw + (size_t)dst*128 + seg*16 + half*8);
    float* rr = r + half*8;
    rr[0]+=bf2f((u16)(vn.x&0xffffu))+bf2f((u16)(vf.x&0xffffu));
    rr[1]+=bf2f((u16)(vn.x>>16))+bf2f((u16)(vf.x>>16));
    rr[2]+=bf2f((u16)(vn.y&0xffffu))+bf2f((u16)(vf.y&0xffffu));
    rr[3]+=bf2f((u16)(vn.y>>16))+bf2f((u16)(vf.y>>16));
    rr[4]+=bf2f((u16)(vn.z&0xffffu))+bf2f((u16)(vf.z&0xffffu));
    rr[5]+=bf2f((u16)(vn.z>>16))+bf2f((u16)(vf.z>>16));
    rr[6]+=bf2f((u16)(vn.w&0xffffu))+bf2f((u16)(vf.w&0xffffu));
    rr[7]+=bf2f((u16)(vn.w>>16))+bf2f((u16)(vf.w>>16));
  }
  float4* o4 = (float4*)(outp + (size_t)e*DD + seg*16);
  #pragma unroll
  for (int i = 0; i < 4; ++i)
    o4[i] = make_float4(r[4*i], r[4*i+1], r[4*i+2], r[4*i+3]);
}

// one wave per node: msg[n] = SUM over CSR range of relu(eps[i] + proj[oth[i]])
// sta = START offsets now (no fill-pass cursor mutation)
__global__ __launch_bounds__(256) void k_gather2(const int* __restrict__ sta,
                                                 const int* __restrict__ cnt,
                                                 const int* __restrict__ oth,
                                                 const u16* __restrict__ eps,
                                                 const u16* __restrict__ proj,
                                                 float* __restrict__ msg) {
  const int n = blockIdx.x*4 + (threadIdx.x >> 6);
  const int lane = threadIdx.x & 63;
  const int start = sta[n];
  const int c = cnt[n];
  const int end = start + c;
  float acc = 0.f;
  #pragma unroll 4
  for (int i = start; i < end; ++i) {
    const int o = oth[i];
    acc += fmaxf(bf2f(eps[(size_t)i*DD + lane]) + bf2f(proj[(size_t)o*DD + lane]), 0.f);
  }
  msg[(size_t)n*DD + lane] = acc;
}

extern "C" void kernel_launch(void* const* d_in, const int* in_sizes, int n_in,
                              void* d_out, int out_size, void* d_ws, size_t ws_size,
                              hipStream_t stream) {
  if (ws_size < (size_t)WS_FLOATS * 4) return;
  const float* node = (const float*)d_in[0];
  const float* eemb = (const float*)d_in[1];
  const float* feat = (const float*)d_in[2];
  const u32*   eidx = (const u32*)d_in[3];
  const float* P  = (const float*)d_in[4];
  const float* bP = (const float*)d_in[5];
  const float* Q  = (const float*)d_in[6];
  const float* bQ = (const float*)d_in[7];
  const float* W  = (const float*)d_in[8];
  const float* bW = (const float*)d_in[9];
  float* wsf = (float*)d_ws;
  int*   wsi = (int*)d_ws;
  float* out = (float*)d_out;

  u16* Fp_h = (u16*)out;
  u16* epN_h = (u16*)(out + (size_t)ND*DD);
  u16* epF_h = epN_h + (size_t)NE*DD;
  u16* Np_h = (u16*)(out + (size_t)(ND + NE)*DD);
  float* msgN = wsf + OFF_MSGN;
  float* msgF = wsf + OFF_MSGF;
  int* rankN = (int*)(wsf + OFF_MSGN);  // overlays msgN start; dead after k_epm
  int* rankF = rankN + NE;
  u16* Bpk = (u16*)(wsf + OFF_BPK);     // [P1|W0|Q0|Q1|W1|W2] x 4096

  hipMemsetAsync((void*)(wsi + OFF_CNTN), 0, (size_t)100000 * 4, stream);
  k_detect<<<1, 256, 0, stream>>>(eidx, wsi + OFF_FLAGS);
  k_bpack6<<<96, 256, 0, stream>>>(P + 64*DD, W, Q, Q + 64*DD, W + 64*DD, W + 128*DD, Bpk);
  k_hist2<<<EBLK, 256, 0, stream>>>(eidx, wsi + OFF_CNTN, wsi + OFF_CNTF,
                                    rankN, rankF, wsi + OFF_FLAGS);
  k_scan<<<2, 1024, 0, stream>>>(wsi + OFF_CNTN, wsi + OFF_STAN);
  k_proj<<<NBLK, 256, 0, stream>>>(feat, P, Fp_h);
  k_proj<<<NBLK, 256, 0, stream>>>(node, P, Np_h);
  k_epm<<<12500, 256, 0, stream>>>(eemb, eidx, Bpk, bP,
                                   wsi + OFF_STAN, wsi + OFF_STAF,
                                   rankN, rankF,
                                   wsi + OFF_OTHN, wsi + OFF_OTHF,
                                   epN_h, epF_h, wsi + OFF_FLAGS);
  // gatherN overwrites the rank arrays (dead after k_epm)
  k_gather2<<<12500, 256, 0, stream>>>(wsi + OFF_STAN, wsi + OFF_CNTN,
                                       wsi + OFF_OTHN, epN_h, Fp_h, msgN);
  k_gather2<<<12500, 256, 0, stream>>>(wsi + OFF_STAF, wsi + OFF_CNTF,
                                       wsi + OFF_OTHF, epF_h, Np_h, msgF);
  k_updm<<<2*UBLK, 256, 0, stream>>>(node, feat, wsi + OFF_CNTN, wsi + OFF_CNTF,
                                     msgN, msgF, Bpk, bQ,
                                     out, out + (size_t)(ND + NE)*DD);
  k_eoutm<<<12500, 256, 0, stream>>>(eemb, eidx, Bpk + 4096, bW,
                                     (const u16*)msgN, (const u16*)msgF,
                                     out + (size_t)ND*DD, wsi + OFF_FLAGS);
}

// Round 16
// 533.019 us; speedup vs baseline: 2.7861x; 1.0167x over previous
//
#include <hip/hip_runtime.h>

typedef unsigned int u32;
typedef unsigned short u16;
using bf16x8 = __attribute__((ext_vector_type(8))) short;
using f32x4  = __attribute__((ext_vector_type(4))) float;

#define ND 50000
#define NF 50000
#define NE 800000
#define DD 64
#define NBLK 196   // ceil(50000/256)
#define EBLK 3125  // 800000/256
#define UBLK 782   // ceil(50000/64)

// ---- ws float-index layout ----
#define OFF_FLAGS 0                        // [0] = idx-is-int64
#define OFF_CNTN  64
#define OFF_CNTF  (OFF_CNTN + 50000)
#define OFF_STAN  (OFF_CNTF + 50000)       // start offsets (never mutated after scan)
#define OFF_STAF  (OFF_STAN + 50000)
#define OFF_OTHN  (OFF_STAF + 50000)
#define OFF_OTHF  (OFF_OTHN + 800000)
#define OFF_MSGN  (OFF_OTHF + 800000)      // first 1.6M floats: rankN/rankF (dead after k_epm)
#define OFF_MSGF  (OFF_MSGN + 3200000)
#define OFF_BPK   (OFF_MSGF + 3200000)     // 12288 floats: 6*4096 bf16 B-frags
                                           // [P1 | W0 | Q0 | Q1 | W1 | W2]
#define WS_FLOATS (OFF_BPK + 12288)

__device__ __forceinline__ u16 f2bf(float x){ union{u32 u;float f;}v; v.f=x; u32 r=v.u+0x7fffu+((v.u>>16)&1u); return (u16)(r>>16); }
__device__ __forceinline__ float bf2f(u16 h){ union{u32 u;float f;}v; v.u=((u32)h)<<16; return v.f; }
__device__ __forceinline__ u32 pk2(float a,float b){ return (u32)f2bf(a) | ((u32)f2bf(b)<<16); }

// swizzled LDS byte offset for 128B bf16 rows / 256B fp32 rows
#define LDSW(row, b)  ((row)*128 + ((b) ^ (((row)&7)<<4)))
#define LDSWF(row, b) ((row)*256 + ((b) ^ (((row)&3)<<6)))

__global__ __launch_bounds__(256) void k_detect(const u32* __restrict__ idxw,
                                                int* __restrict__ flags) {
  __shared__ int cn;
  if (threadIdx.x == 0) cn = 0;
  __syncthreads();
  int c = 0;
  for (int k = 0; k < 16; ++k)
    c += (idxw[2*(threadIdx.x + k*256) + 1] != 0u) ? 1 : 0;
  atomicAdd(&cn, c);
  __syncthreads();
  if (threadIdx.x == 0) flags[0] = (cn == 0) ? 1 : 0;
}

// zero the cnt arrays (replaces hipMemsetAsync / rocclr fillBuffer in the graph)
__global__ __launch_bounds__(256) void k_zero(int* __restrict__ p) {
  const int i = blockIdx.x*256 + threadIdx.x;
  if (i < 100000) p[i] = 0;
}

// histogram + per-edge rank capture
__global__ __launch_bounds__(256) void k_hist2(const u32* __restrict__ eidx,
                                               int* __restrict__ cntN,
                                               int* __restrict__ cntF,
                                               int* __restrict__ rankN,
                                               int* __restrict__ rankF,
                                               const int* __restrict__ flags) {
  const int e = blockIdx.x*256 + threadIdx.x;
  const int I64 = flags[0];
  const u32 src = I64 ? eidx[2*(size_t)e]        : eidx[e];
  const u32 dst = I64 ? eidx[2*((size_t)NE + e)] : eidx[(size_t)NE + e];
  rankN[e] = atomicAdd(cntN + src, 1);
  rankF[e] = atomicAdd(cntF + dst, 1);
}

__global__ __launch_bounds__(1024) void k_scan(const int* __restrict__ cnt,
                                               int* __restrict__ sta) {
  const int base = blockIdx.x * 50000;
  const int t = threadIdx.x;
  __shared__ int part[1024];
  int local[49];
  int s = 0;
  const int start = t * 49;
  #pragma unroll
  for (int j = 0; j < 49; ++j) {
    const int idx = start + j;
    const int v = (idx < 50000) ? cnt[base + idx] : 0;
    local[j] = s;
    s += v;
  }
  part[t] = s;
  __syncthreads();
  for (int off = 1; off < 1024; off <<= 1) {
    int v = 0;
    if (t >= off) v = part[t - off];
    __syncthreads();
    if (t >= off) part[t] += v;
    __syncthreads();
  }
  const int bv = (t > 0) ? part[t - 1] : 0;
  #pragma unroll
  for (int j = 0; j < 49; ++j) {
    const int idx = start + j;
    if (idx < 50000) sta[base + idx] = bv + local[j];
  }
}

// pack 6 matrices (each 64x64 fp32, K x N) into MFMA B-fragments (bf16)
__global__ __launch_bounds__(256) void k_bpack6(const float* __restrict__ P1,
                                                const float* __restrict__ W0,
                                                const float* __restrict__ Q0,
                                                const float* __restrict__ Q1,
                                                const float* __restrict__ W1,
                                                const float* __restrict__ W2,
                                                u16* __restrict__ Bpk) {
  const int v = blockIdx.x*256 + threadIdx.x;   // 0..24575
  const int mi = v >> 12;
  const int vv = v & 4095;
  const int f = vv >> 9, rem = vv & 511;
  const int lane = rem >> 3, j = rem & 7;
  const int kk = f >> 2, nt = f & 3;
  const int k = kk*32 + (lane>>4)*8 + j;
  const int col = nt*16 + (lane&15);
  const float* __restrict__ S = (mi==0) ? P1 : (mi==1) ? W0 : (mi==2) ? Q0
                              : (mi==3) ? Q1 : (mi==4) ? W1 : W2;
  Bpk[v] = f2bf(S[k*64 + col]);
}

// proj[row] (bf16) = emb[row] @ wt    (round-10 proven)
__global__ __launch_bounds__(256) void k_proj(const float* __restrict__ emb,
                                              const float* __restrict__ wt,
                                              u16* __restrict__ outp) {
  const int row = blockIdx.x*256 + threadIdx.x;
  if (row >= 50000) return;
  float acc[DD];
  #pragma unroll
  for (int c = 0; c < DD; ++c) acc[c] = 0.f;
  #pragma unroll 4
  for (int k4 = 0; k4 < 16; ++k4) {
    const float4 v = *(const float4*)(emb + (size_t)row*DD + k4*4);
    const float f[4] = {v.x, v.y, v.z, v.w};
    const float* __restrict__ wr = wt + k4*4*DD;
    #pragma unroll
    for (int c = 0; c < DD; ++c) {
      float a = acc[c];
      #pragma unroll
      for (int j = 0; j < 4; ++j) a = fmaf(f[j], wr[j*DD + c], a);
      acc[c] = a;
    }
  }
  uint4 s[8]; u32* sw = (u32*)s;
  #pragma unroll
  for (int i = 0; i < 32; ++i) sw[i] = pk2(acc[2*i], acc[2*i+1]);
  uint4* o4 = (uint4*)(outp + (size_t)row*DD);
  #pragma unroll
  for (int i = 0; i < 8; ++i) o4[i] = s[i];
}

// MFMA ep: X(64x64)@P1 + bP -> bf16 rows scattered to CSR slots (round-15 proven)
__global__ __launch_bounds__(256) void k_epm(const float* __restrict__ eemb,
                                             const u32* __restrict__ eidx,
                                             const u16* __restrict__ Bpk,
                                             const float* __restrict__ bP,
                                             const int* __restrict__ staN,
                                             const int* __restrict__ staF,
                                             const int* __restrict__ rankN,
                                             const int* __restrict__ rankF,
                                             int* __restrict__ othN,
                                             int* __restrict__ othF,
                                             u16* __restrict__ epN,
                                             u16* __restrict__ epF,
                                             const int* __restrict__ flags) {
  __shared__ u16 lds[4096];
  const int t = threadIdx.x;
  const int e0 = blockIdx.x * 64;
  #pragma unroll
  for (int i = 0; i < 4; ++i) {
    const int g = i*256 + t;
    const float4 v = ((const float4*)(eemb + (size_t)e0*DD))[g];
    const int row = g >> 4;
    const int b   = (g & 15) * 8;
    *(uint2*)((char*)lds + LDSW(row, b)) = make_uint2(pk2(v.x, v.y), pk2(v.z, v.w));
  }
  __syncthreads();
  const int w = t >> 6, l = t & 63;
  bf16x8 bf[8];
  #pragma unroll
  for (int f = 0; f < 8; ++f)
    bf[f] = *(const bf16x8*)(Bpk + (f*64 + l)*8);
  f32x4 acc[4];
  #pragma unroll
  for (int nt = 0; nt < 4; ++nt) {
    const float b = bP[nt*16 + (l&15)];
    acc[nt] = (f32x4){b, b, b, b};
  }
  const int arow = w*16 + (l&15);
  const bf16x8 a0 = *(const bf16x8*)((char*)lds + LDSW(arow, (l>>4)*16));
  const bf16x8 a1 = *(const bf16x8*)((char*)lds + LDSW(arow, 64 + (l>>4)*16));
  #pragma unroll
  for (int nt = 0; nt < 4; ++nt) {
    acc[nt] = __builtin_amdgcn_mfma_f32_16x16x32_bf16(a0, bf[nt],     acc[nt], 0, 0, 0);
    acc[nt] = __builtin_amdgcn_mfma_f32_16x16x32_bf16(a1, bf[4 + nt], acc[nt], 0, 0, 0);
  }
  #pragma unroll
  for (int nt = 0; nt < 4; ++nt) {
    #pragma unroll
    for (int r = 0; r < 4; ++r) {
      const int row = w*16 + (l>>4)*4 + r;
      const int col = nt*16 + (l&15);
      *(u16*)((char*)lds + LDSW(row, col*2)) = f2bf(acc[nt][r]);
    }
  }
  const int lr = l >> 2, seg = l & 3;
  const int row = w*16 + lr;
  const int e = e0 + row;
  const int I64 = flags[0];
  const u32 src = I64 ? eidx[2*(size_t)e]        : eidx[e];
  const u32 dst = I64 ? eidx[2*((size_t)NE + e)] : eidx[(size_t)NE + e];
  const int pN = staN[src] + rankN[e];
  const int pF = staF[dst] + rankF[e];
  if (seg == 0) { othN[pN] = (int)dst; othF[pF] = (int)src; }
  const uint4 c0 = *(const uint4*)((char*)lds + LDSW(row, seg*32));
  const uint4 c1 = *(const uint4*)((char*)lds + LDSW(row, seg*32 + 16));
  *(uint4*)(epN + (size_t)pN*DD + seg*16)     = c0;
  *(uint4*)(epN + (size_t)pN*DD + seg*16 + 8) = c1;
  *(uint4*)(epF + (size_t)pF*DD + seg*16)     = c0;
  *(uint4*)(epF + (size_t)pF*DD + seg*16 + 8) = c1;
}

// MFMA update (round-14 proven)
__global__ __launch_bounds__(256) void k_updm(const float* __restrict__ node,
                                              const float* __restrict__ feat,
                                              const int* __restrict__ cntN,
                                              const int* __restrict__ cntF,
                                              float* msgN, float* msgF,
                                              const u16* __restrict__ Bpk,
                                              const float* __restrict__ bQ,
                                              float* __restrict__ outN,
                                              float* __restrict__ outF) {
  __shared__ char lb[40960];  // A1[0,8K) A2[8K,16K) C1h[16K,24K) C1f[24K,40K)
  const int t = threadIdx.x;
  const bool isN = blockIdx.x < UBLK;
  const int b = isN ? (int)blockIdx.x : (int)blockIdx.x - UBLK;
  const int r0 = b * 64;
  const float* __restrict__ emb = isN ? node : feat;
  const int* __restrict__ cnt = isN ? cntN : cntF;
  float* msgp = isN ? msgN : msgF;
  float* __restrict__ outp = isN ? outN : outF;
  const u16* __restrict__ BQ0 = Bpk + 2*4096;
  const u16* __restrict__ BQ1 = Bpk + 3*4096;
  const u16* __restrict__ BW  = Bpk + (isN ? 4 : 5)*4096;

  #pragma unroll
  for (int i = 0; i < 4; ++i) {
    const int g = i*256 + t;
    const int row = g >> 4;
    const int grow = r0 + row;
    const int q = g & 15;
    float4 v1 = make_float4(0.f, 0.f, 0.f, 0.f), v2 = v1;
    if (grow < 50000) {
      v1 = ((const float4*)(emb + (size_t)grow*DD))[q];
      const float inv = 1.f / fmaxf((float)cnt[grow], 1.f);
      const float4 mm = ((const float4*)(msgp + (size_t)grow*DD))[q];
      v2 = make_float4(mm.x*inv, mm.y*inv, mm.z*inv, mm.w*inv);
    }
    *(uint2*)(lb + LDSW(row, q*8))        = make_uint2(pk2(v1.x,v1.y), pk2(v1.z,v1.w));
    *(uint2*)(lb + 8192 + LDSW(row, q*8)) = make_uint2(pk2(v2.x,v2.y), pk2(v2.z,v2.w));
  }
  __syncthreads();
  const int w = t >> 6, l = t & 63;
  bf16x8 q0f[8], q1f[8];
  #pragma unroll
  for (int f = 0; f < 8; ++f) {
    q0f[f] = *(const bf16x8*)(BQ0 + (f*64 + l)*8);
    q1f[f] = *(const bf16x8*)(BQ1 + (f*64 + l)*8);
  }
  f32x4 acc[4];
  #pragma unroll
  for (int nt = 0; nt < 4; ++nt) {
    const float bb = bQ[nt*16 + (l&15)];
    acc[nt] = (f32x4){bb, bb, bb, bb};
  }
  const int arow = w*16 + (l&15);
  const bf16x8 e0 = *(const bf16x8*)(lb + LDSW(arow, (l>>4)*16));
  const bf16x8 e1 = *(const bf16x8*)(lb + LDSW(arow, 64 + (l>>4)*16));
  const bf16x8 m0 = *(const bf16x8*)(lb + 8192 + LDSW(arow, (l>>4)*16));
  const bf16x8 m1 = *(const bf16x8*)(lb + 8192 + LDSW(arow, 64 + (l>>4)*16));
  #pragma unroll
  for (int nt = 0; nt < 4; ++nt) {
    acc[nt] = __builtin_amdgcn_mfma_f32_16x16x32_bf16(e0, q0f[nt],   acc[nt], 0, 0, 0);
    acc[nt] = __builtin_amdgcn_mfma_f32_16x16x32_bf16(e1, q0f[4+nt], acc[nt], 0, 0, 0);
    acc[nt] = __builtin_amdgcn_mfma_f32_16x16x32_bf16(m0, q1f[nt],   acc[nt], 0, 0, 0);
    acc[nt] = __builtin_amdgcn_mfma_f32_16x16x32_bf16(m1, q1f[4+nt], acc[nt], 0, 0, 0);
  }
  #pragma unroll
  for (int nt = 0; nt < 4; ++nt) {
    #pragma unroll
    for (int r = 0; r < 4; ++r) {
      const int row = w*16 + (l>>4)*4 + r;
      const int col = nt*16 + (l&15);
      const float val = acc[nt][r];
      *(float*)(lb + 24576 + LDSWF(row, col*4)) = val;
      *(u16*)(lb + 16384 + LDSW(row, col*2)) = f2bf(val);
    }
  }
  #pragma unroll
  for (int i = 0; i < 4; ++i) {
    const int row = w*16 + i*4 + (l>>4);
    const int grow = r0 + row;
    if (grow < 50000) {
      const uint4 vv = *(const uint4*)(lb + 24576 + LDSWF(row, (l&15)*16));
      *(uint4*)((u32*)(outp + (size_t)grow*DD) + (l&15)*4) = vv;
    }
  }
  bf16x8 wf[8];
  #pragma unroll
  for (int f = 0; f < 8; ++f)
    wf[f] = *(const bf16x8*)(BW + (f*64 + l)*8);
  f32x4 acc2[4];
  #pragma unroll
  for (int nt = 0; nt < 4; ++nt) acc2[nt] = (f32x4){0.f, 0.f, 0.f, 0.f};
  const bf16x8 c0 = *(const bf16x8*)(lb + 16384 + LDSW(arow, (l>>4)*16));
  const bf16x8 c1 = *(const bf16x8*)(lb + 16384 + LDSW(arow, 64 + (l>>4)*16));
  #pragma unroll
  for (int nt = 0; nt < 4; ++nt) {
    acc2[nt] = __builtin_amdgcn_mfma_f32_16x16x32_bf16(c0, wf[nt],   acc2[nt], 0, 0, 0);
    acc2[nt] = __builtin_amdgcn_mfma_f32_16x16x32_bf16(c1, wf[4+nt], acc2[nt], 0, 0, 0);
  }
  #pragma unroll
  for (int nt = 0; nt < 4; ++nt) {
    #pragma unroll
    for (int r = 0; r < 4; ++r) {
      const int row = w*16 + (l>>4)*4 + r;
      const int col = nt*16 + (l&15);
      *(u16*)(lb + LDSW(row, col*2)) = f2bf(acc2[nt][r]);
    }
  }
  #pragma unroll
  for (int i = 0; i < 2; ++i) {
    const int row = w*16 + i*8 + (l>>3);
    const int grow = r0 + row;
    if (grow < 50000) {
      const uint4 vv = *(const uint4*)(lb + LDSW(row, (l&7)*16));
      *(uint4*)((u16*)(msgp + (size_t)grow*DD) + (l&7)*8) = vv;
    }
  }
}

// MFMA edge_out (round-13 proven)
__global__ __launch_bounds__(256) void k_eoutm(const float* __restrict__ eemb,
                                               const u32* __restrict__ eidx,
                                               const u16* __restrict__ BpkW,
                                               const float* __restrict__ bW,
                                               const u16* __restrict__ NOw,
                                               const u16* __restrict__ FOw,
                                               float* __restrict__ outp,
                                               const int* __restrict__ flags) {
  __shared__ u16 lds[4096];
  const int t = threadIdx.x;
  const int e0 = blockIdx.x * 64;
  #pragma unroll
  for (int i = 0; i < 4; ++i) {
    const int g = i*256 + t;
    const float4 v = ((const float4*)(eemb + (size_t)e0*DD))[g];
    const int row = g >> 4;
    const int b   = (g & 15) * 8;
    *(uint2*)((char*)lds + LDSW(row, b)) = make_uint2(pk2(v.x, v.y), pk2(v.z, v.w));
  }
  __syncthreads();
  const int w = t >> 6, l = t & 63;
  bf16x8 bf[8];
  #pragma unroll
  for (int f = 0; f < 8; ++f)
    bf[f] = *(const bf16x8*)(BpkW + (f*64 + l)*8);
  f32x4 acc[4];
  #pragma unroll
  for (int nt = 0; nt < 4; ++nt) {
    const float b = bW[nt*16 + (l&15)];
    acc[nt] = (f32x4){b, b, b, b};
  }
  const int arow = w*16 + (l&15);
  const bf16x8 a0 = *(const bf16x8*)((char*)lds + LDSW(arow, (l>>4)*16));
  const bf16x8 a1 = *(const bf16x8*)((char*)lds + LDSW(arow, 64 + (l>>4)*16));
  #pragma unroll
  for (int nt = 0; nt < 4; ++nt) {
    acc[nt] = __builtin_amdgcn_mfma_f32_16x16x32_bf16(a0, bf[nt],     acc[nt], 0, 0, 0);
    acc[nt] = __builtin_amdgcn_mfma_f32_16x16x32_bf16(a1, bf[4 + nt], acc[nt], 0, 0, 0);
  }
  #pragma unroll
  for (int nt = 0; nt < 4; ++nt) {
    #pragma unroll
    for (int r = 0; r < 4; ++r) {
      const int row = w*16 + (l>>4)*4 + r;
      const int col = nt*16 + (l&15);
      *(u16*)((char*)lds + LDSW(row, col*2)) = f2bf(acc[nt][r]);
    }
  }
  const int lr = l >> 2, seg = l & 3;
  const int row = w*16 + lr;
  const int e = e0 + row;
  const int I64 = flags[0];
  const u32 src = I64 ? eidx[2*(size_t)e]        : eidx[e];
  const u32 dst = I64 ? eidx[2*((size_t)NE + e)] : eidx[(size_t)NE + e];
  const uint4 c0 = *(const uint4*)((char*)lds + LDSW(row, seg*32));
  const uint4 c1 = *(const uint4*)((char*)lds + LDSW(row, seg*32 + 16));
  float r[16];
  {
    const uint4 v = c0;
    r[0]=bf2f((u16)(v.x&0xffffu)); r[1]=bf2f((u16)(v.x>>16));
    r[2]=bf2f((u16)(v.y&0xffffu)); r[3]=bf2f((u16)(v.y>>16));
    r[4]=bf2f((u16)(v.z&0xffffu)); r[5]=bf2f((u16)(v.z>>16));
    r[6]=bf2f((u16)(v.w&0xffffu)); r[7]=bf2f((u16)(v.w>>16));
  }
  {
    const uint4 v = c1;
    r[8]=bf2f((u16)(v.x&0xffffu));  r[9]=bf2f((u16)(v.x>>16));
    r[10]=bf2f((u16)(v.y&0xffffu)); r[11]=bf2f((u16)(v.y>>16));
    r[12]=bf2f((u16)(v.z&0xffffu)); r[13]=bf2f((u16)(v.z>>16));
    r[14]=bf2f((u16)(v.w&0xffffu)); r[15]=bf2f((u16)(v.w>>16));
  }
  #pragma unroll
  for (int half = 0; half < 2; ++half) {
    const uint4 vn = *(const uint4*)(NOw + (size_t)src*128 + seg*16 + half*8);
    const uint4 vf = *(const uint4*)(FOw + (size_t)dst*128 + seg*16 + half*8);
    float* rr = r + half*8;
    rr[0]+=bf2f((u16)(vn.x&0xffffu))+bf2f((u16)(vf.x&0xffffu));
    rr[1]+=bf2f((u16)(vn.x>>16))+bf2f((u16)(vf.x>>16));
    rr[2]+=bf2f((u16)(vn.y&0xffffu))+bf2f((u16)(vf.y&0xffffu));
    rr[3]+=bf2f((u16)(vn.y>>16))+bf2f((u16)(vf.y>>16));
    rr[4]+=bf2f((u16)(vn.z&0xffffu))+bf2f((u16)(vf.z&0xffffu));
    rr[5]+=bf2f((u16)(vn.z>>16))+bf2f((u16)(vf.z>>16));
    rr[6]+=bf2f((u16)(vn.w&0xffffu))+bf2f((u16)(vf.w&0xffffu));
    rr[7]+=bf2f((u16)(vn.w>>16))+bf2f((u16)(vf.w>>16));
  }
  float4* o4 = (float4*)(outp + (size_t)e*DD + seg*16);
  #pragma unroll
  for (int i = 0; i < 4; ++i)
    o4[i] = make_float4(r[4*i], r[4*i+1], r[4*i+2], r[4*i+3]);
}

// gather v3: half-wave per edge, u32 (2 channels) per lane.
// lanes 0-31 sum even edges, 32-63 odd edges; combine via shfl_xor(32).
__global__ __launch_bounds__(256) void k_gather3(const int* __restrict__ sta,
                                                 const int* __restrict__ cnt,
                                                 const int* __restrict__ oth,
                                                 const u16* __restrict__ eps,
                                                 const u16* __restrict__ proj,
                                                 float* __restrict__ msg) {
  const int n = blockIdx.x*4 + (threadIdx.x >> 6);
  const int lane = threadIdx.x & 63;
  const int half = lane >> 5;
  const int lh = lane & 31;          // channel pair {2lh, 2lh+1}
  const int start = sta[n];
  const int end = start + cnt[n];
  float a0 = 0.f, a1 = 0.f;
  #pragma unroll 2
  for (int i = start + half; i < end; i += 2) {
    const int o = oth[i];
    const u32 ev = *(const u32*)(eps  + (size_t)i*DD + 2*lh);
    const u32 pv = *(const u32*)(proj + (size_t)o*DD + 2*lh);
    a0 += fmaxf(bf2f((u16)(ev & 0xffffu)) + bf2f((u16)(pv & 0xffffu)), 0.f);
    a1 += fmaxf(bf2f((u16)(ev >> 16))     + bf2f((u16)(pv >> 16)),     0.f);
  }
  a0 += __shfl_xor(a0, 32, 64);
  a1 += __shfl_xor(a1, 32, 64);
  if (half == 0)
    *(float2*)(msg + (size_t)n*DD + 2*lh) = make_float2(a0, a1);
}

extern "C" void kernel_launch(void* const* d_in, const int* in_sizes, int n_in,
                              void* d_out, int out_size, void* d_ws, size_t ws_size,
                              hipStream_t stream) {
  if (ws_size < (size_t)WS_FLOATS * 4) return;
  const float* node = (const float*)d_in[0];
  const float* eemb = (const float*)d_in[1];
  const float* feat = (const float*)d_in[2];
  const u32*   eidx = (const u32*)d_in[3];
  const float* P  = (const float*)d_in[4];
  const float* bP = (const float*)d_in[5];
  const float* Q  = (const float*)d_in[6];
  const float* bQ = (const float*)d_in[7];
  const float* W  = (const float*)d_in[8];
  const float* bW = (const float*)d_in[9];
  float* wsf = (float*)d_ws;
  int*   wsi = (int*)d_ws;
  float* out = (float*)d_out;

  u16* Fp_h = (u16*)out;
  u16* epN_h = (u16*)(out + (size_t)ND*DD);
  u16* epF_h = epN_h + (size_t)NE*DD;
  u16* Np_h = (u16*)(out + (size_t)(ND + NE)*DD);
  float* msgN = wsf + OFF_MSGN;
  float* msgF = wsf + OFF_MSGF;
  int* rankN = (int*)(wsf + OFF_MSGN);  // overlays msgN start; dead after k_epm
  int* rankF = rankN + NE;
  u16* Bpk = (u16*)(wsf + OFF_BPK);     // [P1|W0|Q0|Q1|W1|W2] x 4096

  k_zero<<<391, 256, 0, stream>>>(wsi + OFF_CNTN);
  k_detect<<<1, 256, 0, stream>>>(eidx, wsi + OFF_FLAGS);
  k_bpack6<<<96, 256, 0, stream>>>(P + 64*DD, W, Q, Q + 64*DD, W + 64*DD, W + 128*DD, Bpk);
  k_hist2<<<EBLK, 256, 0, stream>>>(eidx, wsi + OFF_CNTN, wsi + OFF_CNTF,
                                    rankN, rankF, wsi + OFF_FLAGS);
  k_scan<<<2, 1024, 0, stream>>>(wsi + OFF_CNTN, wsi + OFF_STAN);
  k_proj<<<NBLK, 256, 0, stream>>>(feat, P, Fp_h);
  k_proj<<<NBLK, 256, 0, stream>>>(node, P, Np_h);
  k_epm<<<12500, 256, 0, stream>>>(eemb, eidx, Bpk, bP,
                                   wsi + OFF_STAN, wsi + OFF_STAF,
                                   rankN, rankF,
                                   wsi + OFF_OTHN, wsi + OFF_OTHF,
                                   epN_h, epF_h, wsi + OFF_FLAGS);
  k_gather3<<<12500, 256, 0, stream>>>(wsi + OFF_STAN, wsi + OFF_CNTN,
                                       wsi + OFF_OTHN, epN_h, Fp_h, msgN);
  k_gather3<<<12500, 256, 0, stream>>>(wsi + OFF_STAF, wsi + OFF_CNTF,
                                       wsi + OFF_OTHF, epF_h, Np_h, msgF);
  k_updm<<<2*UBLK, 256, 0, stream>>>(node, feat, wsi + OFF_CNTN, wsi + OFF_CNTF,
                                     msgN, msgF, Bpk, bQ,
                                     out, out + (size_t)(ND + NE)*DD);
  k_eoutm<<<12500, 256, 0, stream>>>(eemb, eidx, Bpk + 4096, bW,
                                     (const u16*)msgN, (const u16*)msgF,
                                     out + (size_t)ND*DD, wsi + OFF_FLAGS);
}

// Round 17
// 507.545 us; speedup vs baseline: 2.9260x; 1.0502x over previous
//
#include <hip/hip_runtime.h>

typedef unsigned int u32;
typedef unsigned short u16;
using bf16x8 = __attribute__((ext_vector_type(8))) short;
using f32x4  = __attribute__((ext_vector_type(4))) float;

#define ND 50000
#define NF 50000
#define NE 800000
#define DD 64
#define NBLK 196   // ceil(50000/256)
#define EBLK 3125  // 800000/256
#define UBLK 782   // ceil(50000/64)

// ---- ws float-index layout ----
#define OFF_FLAGS 0                        // [0] = idx-is-int64
#define OFF_CNTN  64
#define OFF_CNTF  (OFF_CNTN + 50000)
#define OFF_STAN  (OFF_CNTF + 50000)       // start offsets (never mutated after scan)
#define OFF_STAF  (OFF_STAN + 50000)
#define OFF_OTHN  (OFF_STAF + 50000)
#define OFF_OTHF  (OFF_OTHN + 800000)
#define OFF_MSGN  (OFF_OTHF + 800000)      // first 1.6M floats: rankN/rankF (dead after k_epm)
#define OFF_MSGF  (OFF_MSGN + 3200000)
#define OFF_BPK   (OFF_MSGF + 3200000)     // 12288 floats: 6*4096 bf16 B-frags
                                           // [P1 | W0 | Q0 | Q1 | W1 | W2]
#define WS_FLOATS (OFF_BPK + 12288)

__device__ __forceinline__ u16 f2bf(float x){ union{u32 u;float f;}v; v.f=x; u32 r=v.u+0x7fffu+((v.u>>16)&1u); return (u16)(r>>16); }
__device__ __forceinline__ float bf2f(u16 h){ union{u32 u;float f;}v; v.u=((u32)h)<<16; return v.f; }
__device__ __forceinline__ u32 pk2(float a,float b){ return (u32)f2bf(a) | ((u32)f2bf(b)<<16); }

// vectorized index fetch (int64 path loads one uint2 instead of two stride-2 words)
__device__ __forceinline__ u32 eidx_at(const u32* __restrict__ eidx, size_t i, int I64) {
  if (I64) return ((const uint2*)eidx)[i].x;
  return eidx[i];
}

// swizzled LDS byte offset for 128B bf16 rows / 256B fp32 rows
#define LDSW(row, b)  ((row)*128 + ((b) ^ (((row)&7)<<4)))
#define LDSWF(row, b) ((row)*256 + ((b) ^ (((row)&3)<<6)))

// merged prologue: blocks [0,391) zero cnt; block 391 detects dtype; [392,488) pack B-frags
__global__ __launch_bounds__(256) void k_pre(const u32* __restrict__ idxw,
                                             int* __restrict__ flags,
                                             int* __restrict__ cnt,        // 100000 ints
                                             const float* __restrict__ P1,
                                             const float* __restrict__ W0,
                                             const float* __restrict__ Q0,
                                             const float* __restrict__ Q1,
                                             const float* __restrict__ W1,
                                             const float* __restrict__ W2,
                                             u16* __restrict__ Bpk) {
  __shared__ int cn;
  const int b = blockIdx.x;
  if (b < 391) {
    const int i = b*256 + threadIdx.x;
    if (i < 100000) cnt[i] = 0;
  } else if (b == 391) {
    if (threadIdx.x == 0) cn = 0;
    __syncthreads();
    int c = 0;
    for (int k = 0; k < 16; ++k)
      c += (idxw[2*(threadIdx.x + k*256) + 1] != 0u) ? 1 : 0;
    atomicAdd(&cn, c);
    __syncthreads();
    if (threadIdx.x == 0) flags[0] = (cn == 0) ? 1 : 0;
  } else {
    const int v = (b - 392)*256 + threadIdx.x;   // 0..24575
    const int mi = v >> 12;
    const int vv = v & 4095;
    const int f = vv >> 9, rem = vv & 511;
    const int lane = rem >> 3, j = rem & 7;
    const int kk = f >> 2, nt = f & 3;
    const int k = kk*32 + (lane>>4)*8 + j;
    const int col = nt*16 + (lane&15);
    const float* __restrict__ S = (mi==0) ? P1 : (mi==1) ? W0 : (mi==2) ? Q0
                                : (mi==3) ? Q1 : (mi==4) ? W1 : W2;
    Bpk[v] = f2bf(S[k*64 + col]);
  }
}

// histogram + per-edge rank capture
__global__ __launch_bounds__(256) void k_hist2(const u32* __restrict__ eidx,
                                               int* __restrict__ cntN,
                                               int* __restrict__ cntF,
                                               int* __restrict__ rankN,
                                               int* __restrict__ rankF,
                                               const int* __restrict__ flags) {
  const int e = blockIdx.x*256 + threadIdx.x;
  const int I64 = flags[0];
  const u32 src = eidx_at(eidx, (size_t)e, I64);
  const u32 dst = eidx_at(eidx, (size_t)NE + e, I64);
  rankN[e] = atomicAdd(cntN + src, 1);
  rankF[e] = atomicAdd(cntF + dst, 1);
}

__global__ __launch_bounds__(1024) void k_scan(const int* __restrict__ cnt,
                                               int* __restrict__ sta) {
  const int base = blockIdx.x * 50000;
  const int t = threadIdx.x;
  __shared__ int part[1024];
  int local[49];
  int s = 0;
  const int start = t * 49;
  #pragma unroll
  for (int j = 0; j < 49; ++j) {
    const int idx = start + j;
    const int v = (idx < 50000) ? cnt[base + idx] : 0;
    local[j] = s;
    s += v;
  }
  part[t] = s;
  __syncthreads();
  for (int off = 1; off < 1024; off <<= 1) {
    int v = 0;
    if (t >= off) v = part[t - off];
    __syncthreads();
    if (t >= off) part[t] += v;
    __syncthreads();
  }
  const int bv = (t > 0) ? part[t - 1] : 0;
  #pragma unroll
  for (int j = 0; j < 49; ++j) {
    const int idx = start + j;
    if (idx < 50000) sta[base + idx] = bv + local[j];
  }
}

// merged proj: blocks [0,196) feat->Fp, [196,392) node->Np
__global__ __launch_bounds__(256) void k_proj2(const float* __restrict__ feat,
                                               const float* __restrict__ node,
                                               const float* __restrict__ wt,
                                               u16* __restrict__ Fp,
                                               u16* __restrict__ Np) {
  const bool isF = blockIdx.x < NBLK;
  const int row = (isF ? (int)blockIdx.x : (int)blockIdx.x - NBLK)*256 + threadIdx.x;
  if (row >= 50000) return;
  const float* __restrict__ emb = isF ? feat : node;
  u16* __restrict__ outp = isF ? Fp : Np;
  float acc[DD];
  #pragma unroll
  for (int c = 0; c < DD; ++c) acc[c] = 0.f;
  #pragma unroll 4
  for (int k4 = 0; k4 < 16; ++k4) {
    const float4 v = *(const float4*)(emb + (size_t)row*DD + k4*4);
    const float f[4] = {v.x, v.y, v.z, v.w};
    const float* __restrict__ wr = wt + k4*4*DD;
    #pragma unroll
    for (int c = 0; c < DD; ++c) {
      float a = acc[c];
      #pragma unroll
      for (int j = 0; j < 4; ++j) a = fmaf(f[j], wr[j*DD + c], a);
      acc[c] = a;
    }
  }
  uint4 s[8]; u32* sw = (u32*)s;
  #pragma unroll
  for (int i = 0; i < 32; ++i) sw[i] = pk2(acc[2*i], acc[2*i+1]);
  uint4* o4 = (uint4*)(outp + (size_t)row*DD);
  #pragma unroll
  for (int i = 0; i < 8; ++i) o4[i] = s[i];
}

// MFMA ep: X(64x64)@P1 + bP -> bf16 rows scattered to CSR slots (round-15 proven)
__global__ __launch_bounds__(256) void k_epm(const float* __restrict__ eemb,
                                             const u32* __restrict__ eidx,
                                             const u16* __restrict__ Bpk,
                                             const float* __restrict__ bP,
                                             const int* __restrict__ staN,
                                             const int* __restrict__ staF,
                                             const int* __restrict__ rankN,
                                             const int* __restrict__ rankF,
                                             int* __restrict__ othN,
                                             int* __restrict__ othF,
                                             u16* __restrict__ epN,
                                             u16* __restrict__ epF,
                                             const int* __restrict__ flags) {
  __shared__ u16 lds[4096];
  const int t = threadIdx.x;
  const int e0 = blockIdx.x * 64;
  #pragma unroll
  for (int i = 0; i < 4; ++i) {
    const int g = i*256 + t;
    const float4 v = ((const float4*)(eemb + (size_t)e0*DD))[g];
    const int row = g >> 4;
    const int b   = (g & 15) * 8;
    *(uint2*)((char*)lds + LDSW(row, b)) = make_uint2(pk2(v.x, v.y), pk2(v.z, v.w));
  }
  __syncthreads();
  const int w = t >> 6, l = t & 63;
  bf16x8 bf[8];
  #pragma unroll
  for (int f = 0; f < 8; ++f)
    bf[f] = *(const bf16x8*)(Bpk + (f*64 + l)*8);
  f32x4 acc[4];
  #pragma unroll
  for (int nt = 0; nt < 4; ++nt) {
    const float b = bP[nt*16 + (l&15)];
    acc[nt] = (f32x4){b, b, b, b};
  }
  const int arow = w*16 + (l&15);
  const bf16x8 a0 = *(const bf16x8*)((char*)lds + LDSW(arow, (l>>4)*16));
  const bf16x8 a1 = *(const bf16x8*)((char*)lds + LDSW(arow, 64 + (l>>4)*16));
  #pragma unroll
  for (int nt = 0; nt < 4; ++nt) {
    acc[nt] = __builtin_amdgcn_mfma_f32_16x16x32_bf16(a0, bf[nt],     acc[nt], 0, 0, 0);
    acc[nt] = __builtin_amdgcn_mfma_f32_16x16x32_bf16(a1, bf[4 + nt], acc[nt], 0, 0, 0);
  }
  #pragma unroll
  for (int nt = 0; nt < 4; ++nt) {
    #pragma unroll
    for (int r = 0; r < 4; ++r) {
      const int row = w*16 + (l>>4)*4 + r;
      const int col = nt*16 + (l&15);
      *(u16*)((char*)lds + LDSW(row, col*2)) = f2bf(acc[nt][r]);
    }
  }
  const int lr = l >> 2, seg = l & 3;
  const int row = w*16 + lr;
  const int e = e0 + row;
  const int I64 = flags[0];
  const u32 src = eidx_at(eidx, (size_t)e, I64);
  const u32 dst = eidx_at(eidx, (size_t)NE + e, I64);
  const int pN = staN[src] + rankN[e];
  const int pF = staF[dst] + rankF[e];
  if (seg == 0) { othN[pN] = (int)dst; othF[pF] = (int)src; }
  const uint4 c0 = *(const uint4*)((char*)lds + LDSW(row, seg*32));
  const uint4 c1 = *(const uint4*)((char*)lds + LDSW(row, seg*32 + 16));
  *(uint4*)(epN + (size_t)pN*DD + seg*16)     = c0;
  *(uint4*)(epN + (size_t)pN*DD + seg*16 + 8) = c1;
  *(uint4*)(epF + (size_t)pF*DD + seg*16)     = c0;
  *(uint4*)(epF + (size_t)pF*DD + seg*16 + 8) = c1;
}

// merged gather: blocks [0,12500) N side, [12500,25000) F side.
// half-wave per edge, u32 (2 channels) per lane; combine via shfl_xor(32).
__global__ __launch_bounds__(256) void k_gather4(const int* __restrict__ staN,
                                                 const int* __restrict__ cntN,
                                                 const int* __restrict__ othN,
                                                 const u16* __restrict__ epN,
                                                 const u16* __restrict__ FpN,
                                                 float* __restrict__ msgN,
                                                 const int* __restrict__ staF,
                                                 const int* __restrict__ cntF,
                                                 const int* __restrict__ othF,
                                                 const u16* __restrict__ epF,
                                                 const u16* __restrict__ NpF,
                                                 float* __restrict__ msgF) {
  const bool isN = blockIdx.x < 12500;
  const int bb = isN ? (int)blockIdx.x : (int)blockIdx.x - 12500;
  const int* __restrict__ sta = isN ? staN : staF;
  const int* __restrict__ cnt = isN ? cntN : cntF;
  const int* __restrict__ oth = isN ? othN : othF;
  const u16* __restrict__ eps = isN ? epN : epF;
  const u16* __restrict__ proj = isN ? FpN : NpF;
  float* __restrict__ msg = isN ? msgN : msgF;

  const int n = bb*4 + (threadIdx.x >> 6);
  const int lane = threadIdx.x & 63;
  const int half = lane >> 5;
  const int lh = lane & 31;          // channel pair {2lh, 2lh+1}
  const int start = sta[n];
  const int end = start + cnt[n];
  float a0 = 0.f, a1 = 0.f;
  #pragma unroll 2
  for (int i = start + half; i < end; i += 2) {
    const int o = oth[i];
    const u32 ev = *(const u32*)(eps  + (size_t)i*DD + 2*lh);
    const u32 pv = *(const u32*)(proj + (size_t)o*DD + 2*lh);
    a0 += fmaxf(bf2f((u16)(ev & 0xffffu)) + bf2f((u16)(pv & 0xffffu)), 0.f);
    a1 += fmaxf(bf2f((u16)(ev >> 16))     + bf2f((u16)(pv >> 16)),     0.f);
  }
  a0 += __shfl_xor(a0, 32, 64);
  a1 += __shfl_xor(a1, 32, 64);
  if (half == 0)
    *(float2*)(msg + (size_t)n*DD + 2*lh) = make_float2(a0, a1);
}

// MFMA update (round-14 proven)
__global__ __launch_bounds__(256) void k_updm(const float* __restrict__ node,
                                              const float* __restrict__ feat,
                                              const int* __restrict__ cntN,
                                              const int* __restrict__ cntF,
                                              float* msgN, float* msgF,
                                              const u16* __restrict__ Bpk,
                                              const float* __restrict__ bQ,
                                              float* __restrict__ outN,
                                              float* __restrict__ outF) {
  __shared__ char lb[40960];  // A1[0,8K) A2[8K,16K) C1h[16K,24K) C1f[24K,40K)
  const int t = threadIdx.x;
  const bool isN = blockIdx.x < UBLK;
  const int b = isN ? (int)blockIdx.x : (int)blockIdx.x - UBLK;
  const int r0 = b * 64;
  const float* __restrict__ emb = isN ? node : feat;
  const int* __restrict__ cnt = isN ? cntN : cntF;
  float* msgp = isN ? msgN : msgF;
  float* __restrict__ outp = isN ? outN : outF;
  const u16* __restrict__ BQ0 = Bpk + 2*4096;
  const u16* __restrict__ BQ1 = Bpk + 3*4096;
  const u16* __restrict__ BW  = Bpk + (isN ? 4 : 5)*4096;

  #pragma unroll
  for (int i = 0; i < 4; ++i) {
    const int g = i*256 + t;
    const int row = g >> 4;
    const int grow = r0 + row;
    const int q = g & 15;
    float4 v1 = make_float4(0.f, 0.f, 0.f, 0.f), v2 = v1;
    if (grow < 50000) {
      v1 = ((const float4*)(emb + (size_t)grow*DD))[q];
      const float inv = 1.f / fmaxf((float)cnt[grow], 1.f);
      const float4 mm = ((const float4*)(msgp + (size_t)grow*DD))[q];
      v2 = make_float4(mm.x*inv, mm.y*inv, mm.z*inv, mm.w*inv);
    }
    *(uint2*)(lb + LDSW(row, q*8))        = make_uint2(pk2(v1.x,v1.y), pk2(v1.z,v1.w));
    *(uint2*)(lb + 8192 + LDSW(row, q*8)) = make_uint2(pk2(v2.x,v2.y), pk2(v2.z,v2.w));
  }
  __syncthreads();
  const int w = t >> 6, l = t & 63;
  bf16x8 q0f[8], q1f[8];
  #pragma unroll
  for (int f = 0; f < 8; ++f) {
    q0f[f] = *(const bf16x8*)(BQ0 + (f*64 + l)*8);
    q1f[f] = *(const bf16x8*)(BQ1 + (f*64 + l)*8);
  }
  f32x4 acc[4];
  #pragma unroll
  for (int nt = 0; nt < 4; ++nt) {
    const float bb = bQ[nt*16 + (l&15)];
    acc[nt] = (f32x4){bb, bb, bb, bb};
  }
  const int arow = w*16 + (l&15);
  const bf16x8 e0 = *(const bf16x8*)(lb + LDSW(arow, (l>>4)*16));
  const bf16x8 e1 = *(const bf16x8*)(lb + LDSW(arow, 64 + (l>>4)*16));
  const bf16x8 m0 = *(const bf16x8*)(lb + 8192 + LDSW(arow, (l>>4)*16));
  const bf16x8 m1 = *(const bf16x8*)(lb + 8192 + LDSW(arow, 64 + (l>>4)*16));
  #pragma unroll
  for (int nt = 0; nt < 4; ++nt) {
    acc[nt] = __builtin_amdgcn_mfma_f32_16x16x32_bf16(e0, q0f[nt],   acc[nt], 0, 0, 0);
    acc[nt] = __builtin_amdgcn_mfma_f32_16x16x32_bf16(e1, q0f[4+nt], acc[nt], 0, 0, 0);
    acc[nt] = __builtin_amdgcn_mfma_f32_16x16x32_bf16(m0, q1f[nt],   acc[nt], 0, 0, 0);
    acc[nt] = __builtin_amdgcn_mfma_f32_16x16x32_bf16(m1, q1f[4+nt], acc[nt], 0, 0, 0);
  }
  #pragma unroll
  for (int nt = 0; nt < 4; ++nt) {
    #pragma unroll
    for (int r = 0; r < 4; ++r) {
      const int row = w*16 + (l>>4)*4 + r;
      const int col = nt*16 + (l&15);
      const float val = acc[nt][r];
      *(float*)(lb + 24576 + LDSWF(row, col*4)) = val;
      *(u16*)(lb + 16384 + LDSW(row, col*2)) = f2bf(val);
    }
  }
  #pragma unroll
  for (int i = 0; i < 4; ++i) {
    const int row = w*16 + i*4 + (l>>4);
    const int grow = r0 + row;
    if (grow < 50000) {
      const uint4 vv = *(const uint4*)(lb + 24576 + LDSWF(row, (l&15)*16));
      *(uint4*)((u32*)(outp + (size_t)grow*DD) + (l&15)*4) = vv;
    }
  }
  bf16x8 wf[8];
  #pragma unroll
  for (int f = 0; f < 8; ++f)
    wf[f] = *(const bf16x8*)(BW + (f*64 + l)*8);
  f32x4 acc2[4];
  #pragma unroll
  for (int nt = 0; nt < 4; ++nt) acc2[nt] = (f32x4){0.f, 0.f, 0.f, 0.f};
  const bf16x8 c0 = *(const bf16x8*)(lb + 16384 + LDSW(arow, (l>>4)*16));
  const bf16x8 c1 = *(const bf16x8*)(lb + 16384 + LDSW(arow, 64 + (l>>4)*16));
  #pragma unroll
  for (int nt = 0; nt < 4; ++nt) {
    acc2[nt] = __builtin_amdgcn_mfma_f32_16x16x32_bf16(c0, wf[nt],   acc2[nt], 0, 0, 0);
    acc2[nt] = __builtin_amdgcn_mfma_f32_16x16x32_bf16(c1, wf[4+nt], acc2[nt], 0, 0, 0);
  }
  #pragma unroll
  for (int nt = 0; nt < 4; ++nt) {
    #pragma unroll
    for (int r = 0; r < 4; ++r) {
      const int row = w*16 + (l>>4)*4 + r;
      const int col = nt*16 + (l&15);
      *(u16*)(lb + LDSW(row, col*2)) = f2bf(acc2[nt][r]);
    }
  }
  #pragma unroll
  for (int i = 0; i < 2; ++i) {
    const int row = w*16 + i*8 + (l>>3);
    const int grow = r0 + row;
    if (grow < 50000) {
      const uint4 vv = *(const uint4*)(lb + LDSW(row, (l&7)*16));
      *(uint4*)((u16*)(msgp + (size_t)grow*DD) + (l&7)*8) = vv;
    }
  }
}

// MFMA edge_out (round-13 proven)
__global__ __launch_bounds__(256) void k_eoutm(const float* __restrict__ eemb,
                                               const u32* __restrict__ eidx,
                                               const u16* __restrict__ BpkW,
                                               const float* __restrict__ bW,
                                               const u16* __restrict__ NOw,
                                               const u16* __restrict__ FOw,
                                               float* __restrict__ outp,
                                               const int* __restrict__ flags) {
  __shared__ u16 lds[4096];
  const int t = threadIdx.x;
  const int e0 = blockIdx.x * 64;
  #pragma unroll
  for (int i = 0; i < 4; ++i) {
    const int g = i*256 + t;
    const float4 v = ((const float4*)(eemb + (size_t)e0*DD))[g];
    const int row = g >> 4;
    const int b   = (g & 15) * 8;
    *(uint2*)((char*)lds + LDSW(row, b)) = make_uint2(pk2(v.x, v.y), pk2(v.z, v.w));
  }
  __syncthreads();
  const int w = t >> 6, l = t & 63;
  bf16x8 bf[8];
  #pragma unroll
  for (int f = 0; f < 8; ++f)
    bf[f] = *(const bf16x8*)(BpkW + (f*64 + l)*8);
  f32x4 acc[4];
  #pragma unroll
  for (int nt = 0; nt < 4; ++nt) {
    const float b = bW[nt*16 + (l&15)];
    acc[nt] = (f32x4){b, b, b, b};
  }
  const int arow = w*16 + (l&15);
  const bf16x8 a0 = *(const bf16x8*)((char*)lds + LDSW(arow, (l>>4)*16));
  const bf16x8 a1 = *(const bf16x8*)((char*)lds + LDSW(arow, 64 + (l>>4)*16));
  #pragma unroll
  for (int nt = 0; nt < 4; ++nt) {
    acc[nt] = __builtin_amdgcn_mfma_f32_16x16x32_bf16(a0, bf[nt],     acc[nt], 0, 0, 0);
    acc[nt] = __builtin_amdgcn_mfma_f32_16x16x32_bf16(a1, bf[4 + nt], acc[nt], 0, 0, 0);
  }
  #pragma unroll
  for (int nt = 0; nt < 4; ++nt) {
    #pragma unroll
    for (int r = 0; r < 4; ++r) {
      const int row = w*16 + (l>>4)*4 + r;
      const int col = nt*16 + (l&15);
      *(u16*)((char*)lds + LDSW(row, col*2)) = f2bf(acc[nt][r]);
    }
  }
  const int lr = l >> 2, seg = l & 3;
  const int row = w*16 + lr;
  const int e = e0 + row;
  const int I64 = flags[0];
  const u32 src = eidx_at(eidx, (size_t)e, I64);
  const u32 dst = eidx_at(eidx, (size_t)NE + e, I64);
  const uint4 c0 = *(const uint4*)((char*)lds + LDSW(row, seg*32));
  const uint4 c1 = *(const uint4*)((char*)lds + LDSW(row, seg*32 + 16));
  float r[16];
  {
    const uint4 v = c0;
    r[0]=bf2f((u16)(v.x&0xffffu)); r[1]=bf2f((u16)(v.x>>16));
    r[2]=bf2f((u16)(v.y&0xffffu)); r[3]=bf2f((u16)(v.y>>16));
    r[4]=bf2f((u16)(v.z&0xffffu)); r[5]=bf2f((u16)(v.z>>16));
    r[6]=bf2f((u16)(v.w&0xffffu)); r[7]=bf2f((u16)(v.w>>16));
  }
  {
    const uint4 v = c1;
    r[8]=bf2f((u16)(v.x&0xffffu));  r[9]=bf2f((u16)(v.x>>16));
    r[10]=bf2f((u16)(v.y&0xffffu)); r[11]=bf2f((u16)(v.y>>16));
    r[12]=bf2f((u16)(v.z&0xffffu)); r[13]=bf2f((u16)(v.z>>16));
    r[14]=bf2f((u16)(v.w&0xffffu)); r[15]=bf2f((u16)(v.w>>16));
  }
  #pragma unroll
  for (int half = 0; half < 2; ++half) {
    const uint4 vn = *(const uint4*)(NOw + (size_t)src*128 + seg*16 + half*8);
    const uint4 vf = *(const uint4*)(FOw + (size_t)dst*128 + seg*16 + half*8);
    float* rr = r + half*8;
    rr[0]+=bf2f((u16)(vn.x&0xffffu))+bf2f((u16)(vf.x&0xffffu));
    rr[1]+=bf2f((u16)(vn.x>>16))+bf2f((u16)(vf.x>>16));
    rr[2]+=bf2f((u16)(vn.y&0xffffu))+bf2f((u16)(vf.y&0xffffu));
    rr[3]+=bf2f((u16)(vn.y>>16))+bf2f((u16)(vf.y>>16));
    rr[4]+=bf2f((u16)(vn.z&0xffffu))+bf2f((u16)(vf.z&0xffffu));
    rr[5]+=bf2f((u16)(vn.z>>16))+bf2f((u16)(vf.z>>16));
    rr[6]+=bf2f((u16)(vn.w&0xffffu))+bf2f((u16)(vf.w&0xffffu));
    rr[7]+=bf2f((u16)(vn.w>>16))+bf2f((u16)(vf.w>>16));
  }
  float4* o4 = (float4*)(outp + (size_t)e*DD + seg*16);
  #pragma unroll
  for (int i = 0; i < 4; ++i)
    o4[i] = make_float4(r[4*i], r[4*i+1], r[4*i+2], r[4*i+3]);
}

extern "C" void kernel_launch(void* const* d_in, const int* in_sizes, int n_in,
                              void* d_out, int out_size, void* d_ws, size_t ws_size,
                              hipStream_t stream) {
  if (ws_size < (size_t)WS_FLOATS * 4) return;
  const float* node = (const float*)d_in[0];
  const float* eemb = (const float*)d_in[1];
  const float* feat = (const float*)d_in[2];
  const u32*   eidx = (const u32*)d_in[3];
  const float* P  = (const float*)d_in[4];
  const float* bP = (const float*)d_in[5];
  const float* Q  = (const float*)d_in[6];
  const float* bQ = (const float*)d_in[7];
  const float* W  = (const float*)d_in[8];
  const float* bW = (const float*)d_in[9];
  float* wsf = (float*)d_ws;
  int*   wsi = (int*)d_ws;
  float* out = (float*)d_out;

  u16* Fp_h = (u16*)out;
  u16* epN_h = (u16*)(out + (size_t)ND*DD);
  u16* epF_h = epN_h + (size_t)NE*DD;
  u16* Np_h = (u16*)(out + (size_t)(ND + NE)*DD);
  float* msgN = wsf + OFF_MSGN;
  float* msgF = wsf + OFF_MSGF;
  int* rankN = (int*)(wsf + OFF_MSGN);  // overlays msgN start; dead after k_epm
  int* rankF = rankN + NE;
  u16* Bpk = (u16*)(wsf + OFF_BPK);     // [P1|W0|Q0|Q1|W1|W2] x 4096

  k_pre<<<488, 256, 0, stream>>>(eidx, wsi + OFF_FLAGS, wsi + OFF_CNTN,
                                 P + 64*DD, W, Q, Q + 64*DD, W + 64*DD, W + 128*DD, Bpk);
  k_hist2<<<EBLK, 256, 0, stream>>>(eidx, wsi + OFF_CNTN, wsi + OFF_CNTF,
                                    rankN, rankF, wsi + OFF_FLAGS);
  k_scan<<<2, 1024, 0, stream>>>(wsi + OFF_CNTN, wsi + OFF_STAN);
  k_proj2<<<2*NBLK, 256, 0, stream>>>(feat, node, P, Fp_h, Np_h);
  k_epm<<<12500, 256, 0, stream>>>(eemb, eidx, Bpk, bP,
                                   wsi + OFF_STAN, wsi + OFF_STAF,
                                   rankN, rankF,
                                   wsi + OFF_OTHN, wsi + OFF_OTHF,
                                   epN_h, epF_h, wsi + OFF_FLAGS);
  k_gather4<<<25000, 256, 0, stream>>>(wsi + OFF_STAN, wsi + OFF_CNTN, wsi + OFF_OTHN,
                                       epN_h, Fp_h, msgN,
                                       wsi + OFF_STAF, wsi + OFF_CNTF, wsi + OFF_OTHF,
                                       epF_h, Np_h, msgF);
  k_updm<<<2*UBLK, 256, 0, stream>>>(node, feat, wsi + OFF_CNTN, wsi + OFF_CNTF,
                                     msgN, msgF, Bpk, bQ,
                                     out, out + (size_t)(ND + NE)*DD);
  k_eoutm<<<12500, 256, 0, stream>>>(eemb, eidx, Bpk + 4096, bW,
                                     (const u16*)msgN, (const u16*)msgF,
                                     out + (size_t)ND*DD, wsi + OFF_FLAGS);
}